// Round 1
// baseline (4399.839 us; speedup 1.0000x reference)
//
#include <hip/hip_runtime.h>
#include <cstdint>
#include <cstddef>

// ---------------------------------------------------------------------------
// APPNPNet_Structural: APPNP (K=3) -> FC(128->64)+ReLU -> per-graph softmax
// pooling (weighted segment-max) -> MLP(64->16->1).
// Baseline: fp32 everywhere, scatter-based propagation with global atomics.
// ---------------------------------------------------------------------------

#define DIN 128
#define NEU 64

// ---------------- degree / norm ----------------

__global__ void deg_kernel(const int* __restrict__ dst, float* __restrict__ deg, int E) {
    int i = blockIdx.x * blockDim.x + threadIdx.x;
    int stride = gridDim.x * blockDim.x;
    for (; i < E; i += stride) atomicAdd(&deg[dst[i]], 1.0f);
}

__global__ void rsqrt_kernel(float* __restrict__ deg, int N) {
    int i = blockIdx.x * blockDim.x + threadIdx.x;
    if (i < N) deg[i] = rsqrtf(deg[i] + 1.0f);   // +1 = self loop
}

__global__ void norm_kernel(const int* __restrict__ src, const int* __restrict__ dst,
                            const float* __restrict__ dinv, float* __restrict__ norm, int E) {
    int i = blockIdx.x * blockDim.x + threadIdx.x;
    int stride = gridDim.x * blockDim.x;
    for (; i < E; i += stride) norm[i] = dinv[src[i]] * dinv[dst[i]];
}

// ---------------- APPNP propagation ----------------

// one 64-lane wave per edge; each lane moves a float2 (coalesced 512B row)
__global__ __launch_bounds__(256) void scatter_kernel(
        const int* __restrict__ src, const int* __restrict__ dst,
        const float* __restrict__ norm, const float* __restrict__ h,
        float* __restrict__ agg, int E) {
    int wid = threadIdx.x >> 6;
    int lane = threadIdx.x & 63;
    long long e = (long long)blockIdx.x * 4 + wid;
    if (e >= E) return;
    int s = src[e];
    int d = dst[e];
    float nm = norm[e];
    float2 v = *((const float2*)(h + (size_t)s * DIN) + lane);
    float* ap = agg + (size_t)d * DIN + lane * 2;
    atomicAdd(ap, v.x * nm);
    atomicAdd(ap + 1, v.y * nm);
}

// h_out = 0.9*(agg + dinv^2 * h_in) + 0.1*x   (elementwise, float4)
__global__ void combine_kernel(const float* __restrict__ agg, const float* __restrict__ hin,
                               const float* __restrict__ x, const float* __restrict__ dinv,
                               float* __restrict__ hout, int total4) {
    int i = blockIdx.x * blockDim.x + threadIdx.x;
    int stride = gridDim.x * blockDim.x;
    for (; i < total4; i += stride) {
        int node = i >> 5;                      // 32 float4 per 128-float row
        float dv = dinv[node];
        float d2 = dv * dv;
        float4 a = ((const float4*)agg)[i];
        float4 h = ((const float4*)hin)[i];
        float4 xx = ((const float4*)x)[i];
        float4 o;
        o.x = 0.9f * (a.x + d2 * h.x) + 0.1f * xx.x;
        o.y = 0.9f * (a.y + d2 * h.y) + 0.1f * xx.y;
        o.z = 0.9f * (a.z + d2 * h.z) + 0.1f * xx.z;
        o.w = 0.9f * (a.w + d2 * h.w) + 0.1f * xx.w;
        ((float4*)hout)[i] = o;
    }
}

// ---------------- FC1: h2 = relu(h @ W1 + b1), [N,128]x[128,64] ----------------

__global__ __launch_bounds__(256) void fc1_kernel(
        const float* __restrict__ h, const float* __restrict__ W,
        const float* __restrict__ b, float* __restrict__ out, int N) {
    __shared__ float sW[DIN * NEU];   // 32 KB
    __shared__ float sh[4][DIN];      // 2 KB
    int tid = threadIdx.x;
    for (int k = tid; k < DIN * NEU; k += 256) sW[k] = W[k];
    int n0 = blockIdx.x * 4;
    for (int k = tid; k < 4 * DIN; k += 256) {
        int r = k >> 7, c = k & 127;
        int n = n0 + r;
        sh[r][c] = (n < N) ? h[(size_t)n * DIN + c] : 0.f;
    }
    __syncthreads();
    int j = tid & 63, r = tid >> 6;
    int n = n0 + r;
    if (n < N) {
        float acc = b[j];
#pragma unroll
        for (int k = 0; k < DIN; k++) acc = fmaf(sh[r][k], sW[k * NEU + j], acc);
        out[(size_t)n * NEU + j] = fmaxf(acc, 0.f);
    }
}

// ---------------- closeness logits ----------------

__global__ void logits_kernel(const float* __restrict__ cf, const float* __restrict__ cw,
                              const float* __restrict__ cb, float* __restrict__ logits, int N) {
    int i = blockIdx.x * blockDim.x + threadIdx.x;
    if (i >= N) return;
    const float4* c = (const float4*)(cf + (size_t)i * 8);
    float4 a = c[0], b = c[1];
    float s = a.x * cw[0] + a.y * cw[1] + a.z * cw[2] + a.w * cw[3]
            + b.x * cw[4] + b.y * cw[5] + b.z * cw[6] + b.w * cw[7] + cb[0];
    logits[i] = s;
}

// ---------------- per-graph offsets (batch is sorted) ----------------

__global__ void count_kernel(const int* __restrict__ batch, int* __restrict__ counts, int N) {
    int i = blockIdx.x * blockDim.x + threadIdx.x;
    int stride = gridDim.x * blockDim.x;
    for (; i < N; i += stride) atomicAdd(&counts[batch[i]], 1);
}

__global__ void scan_kernel(const int* __restrict__ counts, int* __restrict__ offs, int G) {
    __shared__ int s[256];
    int tid = threadIdx.x;
    s[tid] = (tid < G) ? counts[tid] : 0;
    __syncthreads();
    for (int d = 1; d < 256; d <<= 1) {
        int v = (tid >= d) ? s[tid - d] : 0;
        __syncthreads();
        s[tid] += v;
        __syncthreads();
    }
    if (tid < G) offs[tid + 1] = s[tid];
    if (tid == 0) offs[0] = 0;
}

// ---------------- segment softmax -> p (scaled by count) ----------------

__global__ __launch_bounds__(256) void softmax_kernel(
        const float* __restrict__ logits, const int* __restrict__ offs,
        float* __restrict__ p, int G) {
    int g = blockIdx.x;
    int s0 = offs[g], e0 = offs[g + 1];
    int tid = threadIdx.x;
    __shared__ float red[256];
    float m = -INFINITY;
    for (int i = s0 + tid; i < e0; i += 256) m = fmaxf(m, logits[i]);
    red[tid] = m; __syncthreads();
    for (int w = 128; w > 0; w >>= 1) {
        if (tid < w) red[tid] = fmaxf(red[tid], red[tid + w]);
        __syncthreads();
    }
    m = red[0]; __syncthreads();
    float z = 0.f;
    for (int i = s0 + tid; i < e0; i += 256) z += expf(logits[i] - m);
    red[tid] = z; __syncthreads();
    for (int w = 128; w > 0; w >>= 1) {
        if (tid < w) red[tid] += red[tid + w];
        __syncthreads();
    }
    z = red[0];
    float scale = (float)(e0 - s0) / z;
    for (int i = s0 + tid; i < e0; i += 256) p[i] = expf(logits[i] - m) * scale;
}

// ---------------- weighted segment max-pool: pooled[g,j] = max_i p[i]*h2[i,j] ----------------

__global__ __launch_bounds__(256) void pool_kernel(
        const float* __restrict__ h2, const float* __restrict__ p,
        const int* __restrict__ offs, float* __restrict__ pooled, int G) {
    int g = blockIdx.x;
    int s0 = offs[g], e0 = offs[g + 1];
    int tid = threadIdx.x;
    int j = tid & 63, r = tid >> 6;
    float mx = -INFINITY;
    for (int i = s0 + r; i < e0; i += 4)
        mx = fmaxf(mx, p[i] * h2[(size_t)i * NEU + j]);
    __shared__ float red[256];
    red[tid] = mx;
    __syncthreads();
    if (r == 0) {
        float m0 = fmaxf(fmaxf(red[j], red[64 + j]), fmaxf(red[128 + j], red[192 + j]));
        pooled[(size_t)g * NEU + j] = m0;
    }
}

// ---------------- final MLP 64->16->1 ----------------

__global__ void final_kernel(const float* __restrict__ pooled, const float* __restrict__ w1,
                             const float* __restrict__ b1, const float* __restrict__ w2,
                             const float* __restrict__ b2, float* __restrict__ out, int G) {
    int g = blockIdx.x;
    int tid = threadIdx.x;   // 64 threads
    __shared__ float sp[64];
    __shared__ float sa[16];
    sp[tid] = pooled[(size_t)g * 64 + tid];
    __syncthreads();
    if (tid < 16) {
        float acc = b1[tid];
#pragma unroll
        for (int k = 0; k < 64; k++) acc = fmaf(sp[k], w1[k * 16 + tid], acc);
        sa[tid] = fmaxf(acc, 0.f);
    }
    __syncthreads();
    if (tid == 0) {
        float o = b2[0];
#pragma unroll
        for (int k = 0; k < 16; k++) o = fmaf(sa[k], w2[k], o);
        out[g] = o;
    }
}

// ---------------------------------------------------------------------------

extern "C" void kernel_launch(void* const* d_in, const int* in_sizes, int n_in,
                              void* d_out, int out_size, void* d_ws, size_t ws_size,
                              hipStream_t stream) {
    const float* x       = (const float*)d_in[0];
    const float* cf      = (const float*)d_in[1];
    const int*   ei      = (const int*)d_in[2];
    const int*   batch   = (const int*)d_in[3];
    // d_in[4] = num_graphs (scalar on device); G == out_size
    const float* nn1_w   = (const float*)d_in[5];
    const float* nn1_b   = (const float*)d_in[6];
    const float* close_w = (const float*)d_in[7];
    const float* close_b = (const float*)d_in[8];
    const float* att1_w  = (const float*)d_in[9];
    const float* att1_b  = (const float*)d_in[10];
    const float* att2_w  = (const float*)d_in[11];
    const float* att2_b  = (const float*)d_in[12];
    float* out = (float*)d_out;

    int N = in_sizes[0] / DIN;
    int E = in_sizes[2] / 2;
    int G = out_size;          // output is [G,1]

    const int* src = ei;
    const int* dst = ei + E;

    char* w = (char*)d_ws;
    size_t off = 0;
    auto alloc = [&](size_t bytes) -> void* {
        void* ptr = w + off;
        off += (bytes + 511) & ~(size_t)511;
        return ptr;
    };
    float* bufA   = (float*)alloc((size_t)N * DIN * 4);   // agg
    float* bufB   = (float*)alloc((size_t)N * DIN * 4);   // h
    float* dinv   = (float*)alloc((size_t)N * 4);
    float* normw  = (float*)alloc((size_t)E * 4);
    float* h2     = (float*)alloc((size_t)N * NEU * 4);
    float* logits = (float*)alloc((size_t)N * 4);
    float* p      = (float*)alloc((size_t)N * 4);
    int*   counts = (int*)alloc((size_t)G * 4);
    int*   offs   = (int*)alloc(((size_t)G + 1) * 4);
    float* pooled = (float*)alloc((size_t)G * NEU * 4);
    (void)ws_size; (void)n_in;

    hipMemsetAsync(dinv, 0, (size_t)N * 4, stream);
    hipMemsetAsync(counts, 0, (size_t)G * 4, stream);

    deg_kernel<<<2048, 256, 0, stream>>>(dst, dinv, E);
    rsqrt_kernel<<<(N + 255) / 256, 256, 0, stream>>>(dinv, N);
    norm_kernel<<<2048, 256, 0, stream>>>(src, dst, dinv, normw, E);

    for (int k = 0; k < 3; k++) {
        const float* hin = (k == 0) ? x : bufB;
        hipMemsetAsync(bufA, 0, (size_t)N * DIN * 4, stream);
        scatter_kernel<<<(E + 3) / 4, 256, 0, stream>>>(src, dst, normw, hin, bufA, E);
        combine_kernel<<<4096, 256, 0, stream>>>(bufA, hin, x, dinv, bufB, N * 32);
    }

    fc1_kernel<<<(N + 3) / 4, 256, 0, stream>>>(bufB, nn1_w, nn1_b, h2, N);
    logits_kernel<<<(N + 255) / 256, 256, 0, stream>>>(cf, close_w, close_b, logits, N);
    count_kernel<<<2048, 256, 0, stream>>>(batch, counts, N);
    scan_kernel<<<1, 256, 0, stream>>>(counts, offs, G);
    softmax_kernel<<<G, 256, 0, stream>>>(logits, offs, p, G);
    pool_kernel<<<G, 256, 0, stream>>>(h2, p, offs, pooled, G);
    final_kernel<<<G, 64, 0, stream>>>(pooled, att1_w, att1_b, att2_w, att2_b, out, G);
}

// Round 2
// 894.050 us; speedup vs baseline: 4.9212x; 4.9212x over previous
//
#include <hip/hip_runtime.h>
#include <cstdint>
#include <cstddef>

// ---------------------------------------------------------------------------
// APPNPNet_Structural: APPNP (K=3) -> FC(128->64)+ReLU -> per-graph softmax
// pooling (weighted segment-max) -> MLP(64->16->1).
// Round 2: pull-based CSR propagation (no f32 atomics, no write amplification).
// ---------------------------------------------------------------------------

#define DIN 128
#define NEU 64

// ---------------- degree histogram (int) ----------------

__global__ void hist_kernel(const int* __restrict__ dst, int* __restrict__ cnt, int E) {
    int i = blockIdx.x * blockDim.x + threadIdx.x;
    int stride = gridDim.x * blockDim.x;
    for (; i < E; i += stride) atomicAdd(&cnt[dst[i]], 1);
}

__global__ void dinv_kernel(const int* __restrict__ cnt, float* __restrict__ dinv, int N) {
    int i = blockIdx.x * blockDim.x + threadIdx.x;
    if (i < N) dinv[i] = rsqrtf((float)cnt[i] + 1.0f);   // +1 = self loop
}

// ---------------- 3-kernel prefix scan of cnt[N] -> rowptr[N+1] ----------------
// chunk = 1024 elements per block (256 thr x 4)

__global__ void scan_chunk_kernel(const int* __restrict__ cnt, int* __restrict__ rp1,
                                  int* __restrict__ bsum, int N) {
    __shared__ int sh[256];
    int t = threadIdx.x;
    int base = blockIdx.x * 1024 + t * 4;
    int a0 = (base + 0 < N) ? cnt[base + 0] : 0;
    int a1 = (base + 1 < N) ? cnt[base + 1] : 0;
    int a2 = (base + 2 < N) ? cnt[base + 2] : 0;
    int a3 = (base + 3 < N) ? cnt[base + 3] : 0;
    int s = a0 + a1 + a2 + a3;
    sh[t] = s; __syncthreads();
    for (int d = 1; d < 256; d <<= 1) {
        int v = (t >= d) ? sh[t - d] : 0;
        __syncthreads();
        sh[t] += v;
        __syncthreads();
    }
    int excl = sh[t] - s;
    if (base + 0 < N) rp1[base + 0] = excl + a0;
    if (base + 1 < N) rp1[base + 1] = excl + a0 + a1;
    if (base + 2 < N) rp1[base + 2] = excl + a0 + a1 + a2;
    if (base + 3 < N) rp1[base + 3] = excl + a0 + a1 + a2 + a3;
    if (t == 255) bsum[blockIdx.x] = sh[255];
}

__global__ void scan_bsum_kernel(int* __restrict__ bsum, int B) {
    __shared__ int sh[256];
    int t = threadIdx.x;
    int run = 0;
    for (int base = 0; base < B; base += 256) {
        int v = (base + t < B) ? bsum[base + t] : 0;
        __syncthreads();
        sh[t] = v; __syncthreads();
        for (int d = 1; d < 256; d <<= 1) {
            int u = (t >= d) ? sh[t - d] : 0;
            __syncthreads();
            sh[t] += u;
            __syncthreads();
        }
        if (base + t < B) bsum[base + t] = run + sh[t] - v;   // exclusive
        run += sh[255];
        __syncthreads();
    }
}

__global__ void add_off_kernel(int* __restrict__ rp1, const int* __restrict__ bsum,
                               int* __restrict__ rowptr0, int N) {
    int t = threadIdx.x;
    int base = blockIdx.x * 1024 + t * 4;
    int off = bsum[blockIdx.x];
#pragma unroll
    for (int j = 0; j < 4; j++)
        if (base + j < N) rp1[base + j] += off;
    if (blockIdx.x == 0 && t == 0) rowptr0[0] = 0;
}

__global__ void copy_kernel(const int* __restrict__ a, int* __restrict__ b, int N) {
    int i = blockIdx.x * blockDim.x + threadIdx.x;
    int stride = gridDim.x * blockDim.x;
    for (; i < N; i += stride) b[i] = a[i];
}

// ---------------- bucket edges by dst ----------------

__global__ void build_csr_kernel(const int* __restrict__ src, const int* __restrict__ dst,
                                 int* __restrict__ cursor, int* __restrict__ es, int E) {
    int i = blockIdx.x * blockDim.x + threadIdx.x;
    int stride = gridDim.x * blockDim.x;
    for (; i < E; i += stride) {
        int pos = atomicAdd(&cursor[dst[i]], 1);
        es[pos] = src[i];
    }
}

// ---------------- fused APPNP pull step ----------------
// one 64-lane wave per dst node; lane holds float2 of the 128-dim row.
// h_out = 0.9*(sum_e norm_e*h[src_e] + dinv^2*h_in) + 0.1*x

__global__ __launch_bounds__(256) void pull_kernel(
        const int* __restrict__ rowptr, const int* __restrict__ es,
        const float* __restrict__ dinv, const float* __restrict__ hin,
        const float* __restrict__ x, float* __restrict__ hout, int N) {
    int wid = threadIdx.x >> 6;
    int lane = threadIdx.x & 63;
    int node = blockIdx.x * 4 + wid;
    if (node >= N) return;
    int beg = rowptr[node], end = rowptr[node + 1];
    float dd = dinv[node];
    float2 acc = make_float2(0.f, 0.f);
    int deg = end - beg;
    for (int base = 0; base < deg; base += 64) {
        int cnt = min(64, deg - base);
        int myi = base + lane;
        int msrc = (myi < deg) ? es[beg + myi] : 0;
        float mns = (myi < deg) ? dinv[msrc] * dd : 0.f;
        for (int j = 0; j < cnt; j++) {
            int s = __shfl(msrc, j);
            float ns = __shfl(mns, j);
            float2 v = *((const float2*)(hin + (size_t)s * DIN) + lane);
            acc.x = fmaf(ns, v.x, acc.x);
            acc.y = fmaf(ns, v.y, acc.y);
        }
    }
    float2 hv = *((const float2*)(hin + (size_t)node * DIN) + lane);
    float2 xv = *((const float2*)(x + (size_t)node * DIN) + lane);
    float d2 = dd * dd;
    float2 o;
    o.x = 0.9f * (acc.x + d2 * hv.x) + 0.1f * xv.x;
    o.y = 0.9f * (acc.y + d2 * hv.y) + 0.1f * xv.y;
    *((float2*)(hout + (size_t)node * DIN) + lane) = o;
}

// ---------------- FC1: h2 = relu(h @ W1 + b1), [N,128]x[128,64] ----------------

__global__ __launch_bounds__(256) void fc1_kernel(
        const float* __restrict__ h, const float* __restrict__ W,
        const float* __restrict__ b, float* __restrict__ out, int N) {
    __shared__ float sW[DIN * NEU];   // 32 KB
    __shared__ float sh[4][DIN];      // 2 KB
    int tid = threadIdx.x;
    for (int k = tid; k < DIN * NEU; k += 256) sW[k] = W[k];
    int n0 = blockIdx.x * 4;
    for (int k = tid; k < 4 * DIN; k += 256) {
        int r = k >> 7, c = k & 127;
        int n = n0 + r;
        sh[r][c] = (n < N) ? h[(size_t)n * DIN + c] : 0.f;
    }
    __syncthreads();
    int j = tid & 63, r = tid >> 6;
    int n = n0 + r;
    if (n < N) {
        float acc = b[j];
#pragma unroll
        for (int k = 0; k < DIN; k++) acc = fmaf(sh[r][k], sW[k * NEU + j], acc);
        out[(size_t)n * NEU + j] = fmaxf(acc, 0.f);
    }
}

// ---------------- closeness logits ----------------

__global__ void logits_kernel(const float* __restrict__ cf, const float* __restrict__ cw,
                              const float* __restrict__ cb, float* __restrict__ logits, int N) {
    int i = blockIdx.x * blockDim.x + threadIdx.x;
    if (i >= N) return;
    const float4* c = (const float4*)(cf + (size_t)i * 8);
    float4 a = c[0], b = c[1];
    float s = a.x * cw[0] + a.y * cw[1] + a.z * cw[2] + a.w * cw[3]
            + b.x * cw[4] + b.y * cw[5] + b.z * cw[6] + b.w * cw[7] + cb[0];
    logits[i] = s;
}

// ---------------- per-graph offsets (batch is sorted) ----------------

__global__ void gcount_kernel(const int* __restrict__ batch, int* __restrict__ gcnt, int N) {
    int i = blockIdx.x * blockDim.x + threadIdx.x;
    int stride = gridDim.x * blockDim.x;
    for (; i < N; i += stride) atomicAdd(&gcnt[batch[i]], 1);
}

__global__ void gscan_kernel(const int* __restrict__ gcnt, int* __restrict__ offs, int G) {
    __shared__ int s[256];
    int tid = threadIdx.x;
    s[tid] = (tid < G) ? gcnt[tid] : 0;
    __syncthreads();
    for (int d = 1; d < 256; d <<= 1) {
        int v = (tid >= d) ? s[tid - d] : 0;
        __syncthreads();
        s[tid] += v;
        __syncthreads();
    }
    if (tid < G) offs[tid + 1] = s[tid];
    if (tid == 0) offs[0] = 0;
}

// ---------------- segment softmax -> p (scaled by count) ----------------

__global__ __launch_bounds__(256) void softmax_kernel(
        const float* __restrict__ logits, const int* __restrict__ offs,
        float* __restrict__ p, int G) {
    int g = blockIdx.x;
    int s0 = offs[g], e0 = offs[g + 1];
    int tid = threadIdx.x;
    __shared__ float red[256];
    float m = -INFINITY;
    for (int i = s0 + tid; i < e0; i += 256) m = fmaxf(m, logits[i]);
    red[tid] = m; __syncthreads();
    for (int w = 128; w > 0; w >>= 1) {
        if (tid < w) red[tid] = fmaxf(red[tid], red[tid + w]);
        __syncthreads();
    }
    m = red[0]; __syncthreads();
    float z = 0.f;
    for (int i = s0 + tid; i < e0; i += 256) z += expf(logits[i] - m);
    red[tid] = z; __syncthreads();
    for (int w = 128; w > 0; w >>= 1) {
        if (tid < w) red[tid] += red[tid + w];
        __syncthreads();
    }
    z = red[0];
    float scale = (float)(e0 - s0) / z;
    for (int i = s0 + tid; i < e0; i += 256) p[i] = expf(logits[i] - m) * scale;
}

// ---------------- weighted segment max-pool ----------------

__global__ __launch_bounds__(256) void pool_kernel(
        const float* __restrict__ h2, const float* __restrict__ p,
        const int* __restrict__ offs, float* __restrict__ pooled, int G) {
    int g = blockIdx.x;
    int s0 = offs[g], e0 = offs[g + 1];
    int tid = threadIdx.x;
    int j = tid & 63, r = tid >> 6;
    float mx = -INFINITY;
    for (int i = s0 + r; i < e0; i += 4)
        mx = fmaxf(mx, p[i] * h2[(size_t)i * NEU + j]);
    __shared__ float red[256];
    red[tid] = mx;
    __syncthreads();
    if (r == 0) {
        float m0 = fmaxf(fmaxf(red[j], red[64 + j]), fmaxf(red[128 + j], red[192 + j]));
        pooled[(size_t)g * NEU + j] = m0;
    }
}

// ---------------- final MLP 64->16->1 ----------------

__global__ void final_kernel(const float* __restrict__ pooled, const float* __restrict__ w1,
                             const float* __restrict__ b1, const float* __restrict__ w2,
                             const float* __restrict__ b2, float* __restrict__ out, int G) {
    int g = blockIdx.x;
    int tid = threadIdx.x;   // 64 threads
    __shared__ float sp[64];
    __shared__ float sa[16];
    sp[tid] = pooled[(size_t)g * 64 + tid];
    __syncthreads();
    if (tid < 16) {
        float acc = b1[tid];
#pragma unroll
        for (int k = 0; k < 64; k++) acc = fmaf(sp[k], w1[k * 16 + tid], acc);
        sa[tid] = fmaxf(acc, 0.f);
    }
    __syncthreads();
    if (tid == 0) {
        float o = b2[0];
#pragma unroll
        for (int k = 0; k < 16; k++) o = fmaf(sa[k], w2[k], o);
        out[g] = o;
    }
}

// ---------------------------------------------------------------------------

extern "C" void kernel_launch(void* const* d_in, const int* in_sizes, int n_in,
                              void* d_out, int out_size, void* d_ws, size_t ws_size,
                              hipStream_t stream) {
    const float* x       = (const float*)d_in[0];
    const float* cf      = (const float*)d_in[1];
    const int*   ei      = (const int*)d_in[2];
    const int*   batch   = (const int*)d_in[3];
    const float* nn1_w   = (const float*)d_in[5];
    const float* nn1_b   = (const float*)d_in[6];
    const float* close_w = (const float*)d_in[7];
    const float* close_b = (const float*)d_in[8];
    const float* att1_w  = (const float*)d_in[9];
    const float* att1_b  = (const float*)d_in[10];
    const float* att2_w  = (const float*)d_in[11];
    const float* att2_b  = (const float*)d_in[12];
    float* out = (float*)d_out;

    int N = in_sizes[0] / DIN;
    int E = in_sizes[2] / 2;
    int G = out_size;

    const int* src = ei;
    const int* dst = ei + E;

    char* w = (char*)d_ws;
    size_t off = 0;
    auto alloc = [&](size_t bytes) -> void* {
        void* ptr = w + off;
        off += (bytes + 511) & ~(size_t)511;
        return ptr;
    };
    float* bufA   = (float*)alloc((size_t)N * DIN * 4);
    float* bufB   = (float*)alloc((size_t)N * DIN * 4);
    float* dinv   = (float*)alloc((size_t)N * 4);
    int*   ncnt   = (int*)alloc((size_t)N * 4);
    int*   rowptr = (int*)alloc(((size_t)N + 1) * 4);
    int*   cursor = (int*)alloc((size_t)N * 4);
    int*   bsum   = (int*)alloc(512 * 4);
    int*   es     = (int*)alloc((size_t)E * 4);
    float* h2     = (float*)alloc((size_t)N * NEU * 4);
    float* logits = (float*)alloc((size_t)N * 4);
    float* p      = (float*)alloc((size_t)N * 4);
    int*   gcnt   = (int*)alloc((size_t)G * 4);
    int*   offs   = (int*)alloc(((size_t)G + 1) * 4);
    float* pooled = (float*)alloc((size_t)G * NEU * 4);
    (void)ws_size; (void)n_in;

    int B = (N + 1023) / 1024;

    hipMemsetAsync(ncnt, 0, (size_t)N * 4, stream);
    hipMemsetAsync(gcnt, 0, (size_t)G * 4, stream);

    // --- CSR build ---
    hist_kernel<<<2048, 256, 0, stream>>>(dst, ncnt, E);
    dinv_kernel<<<(N + 255) / 256, 256, 0, stream>>>(ncnt, dinv, N);
    scan_chunk_kernel<<<B, 256, 0, stream>>>(ncnt, rowptr + 1, bsum, N);
    scan_bsum_kernel<<<1, 256, 0, stream>>>(bsum, B);
    add_off_kernel<<<B, 256, 0, stream>>>(rowptr + 1, bsum, rowptr, N);
    copy_kernel<<<2048, 256, 0, stream>>>(rowptr, cursor, N);
    build_csr_kernel<<<2048, 256, 0, stream>>>(src, dst, cursor, es, E);

    // --- APPNP: 3 fused pull+combine steps ---
    pull_kernel<<<(N + 3) / 4, 256, 0, stream>>>(rowptr, es, dinv, x,    x, bufB, N);
    pull_kernel<<<(N + 3) / 4, 256, 0, stream>>>(rowptr, es, dinv, bufB, x, bufA, N);
    pull_kernel<<<(N + 3) / 4, 256, 0, stream>>>(rowptr, es, dinv, bufA, x, bufB, N);

    // --- head ---
    fc1_kernel<<<(N + 3) / 4, 256, 0, stream>>>(bufB, nn1_w, nn1_b, h2, N);
    logits_kernel<<<(N + 255) / 256, 256, 0, stream>>>(cf, close_w, close_b, logits, N);
    gcount_kernel<<<2048, 256, 0, stream>>>(batch, gcnt, N);
    gscan_kernel<<<1, 256, 0, stream>>>(gcnt, offs, G);
    softmax_kernel<<<G, 256, 0, stream>>>(logits, offs, p, G);
    pool_kernel<<<G, 256, 0, stream>>>(h2, p, offs, pooled, G);
    final_kernel<<<G, 64, 0, stream>>>(pooled, att1_w, att1_b, att2_w, att2_b, out, G);
}

// Round 3
// 696.000 us; speedup vs baseline: 6.3216x; 1.2846x over previous
//
#include <hip/hip_runtime.h>
#include <cstdint>
#include <cstddef>

// ---------------------------------------------------------------------------
// APPNPNet_Structural: APPNP (K=3) -> FC(128->64)+ReLU -> per-graph softmax
// pooling (weighted segment-max) -> MLP(64->16->1).
// Round 3: binary-search graph offsets (batch sorted, no atomics);
//          paired-edge float4 pull; fc1 16 rows/block.
// ---------------------------------------------------------------------------

#define DIN 128
#define NEU 64

// ---------------- degree histogram (int) ----------------

__global__ void hist_kernel(const int* __restrict__ dst, int* __restrict__ cnt, int E) {
    int i = blockIdx.x * blockDim.x + threadIdx.x;
    int stride = gridDim.x * blockDim.x;
    for (; i < E; i += stride) atomicAdd(&cnt[dst[i]], 1);
}

__global__ void dinv_kernel(const int* __restrict__ cnt, float* __restrict__ dinv, int N) {
    int i = blockIdx.x * blockDim.x + threadIdx.x;
    if (i < N) dinv[i] = rsqrtf((float)cnt[i] + 1.0f);   // +1 = self loop
}

// ---------------- 3-kernel prefix scan of cnt[N] -> rowptr[N+1] ----------------

__global__ void scan_chunk_kernel(const int* __restrict__ cnt, int* __restrict__ rp1,
                                  int* __restrict__ bsum, int N) {
    __shared__ int sh[256];
    int t = threadIdx.x;
    int base = blockIdx.x * 1024 + t * 4;
    int a0 = (base + 0 < N) ? cnt[base + 0] : 0;
    int a1 = (base + 1 < N) ? cnt[base + 1] : 0;
    int a2 = (base + 2 < N) ? cnt[base + 2] : 0;
    int a3 = (base + 3 < N) ? cnt[base + 3] : 0;
    int s = a0 + a1 + a2 + a3;
    sh[t] = s; __syncthreads();
    for (int d = 1; d < 256; d <<= 1) {
        int v = (t >= d) ? sh[t - d] : 0;
        __syncthreads();
        sh[t] += v;
        __syncthreads();
    }
    int excl = sh[t] - s;
    if (base + 0 < N) rp1[base + 0] = excl + a0;
    if (base + 1 < N) rp1[base + 1] = excl + a0 + a1;
    if (base + 2 < N) rp1[base + 2] = excl + a0 + a1 + a2;
    if (base + 3 < N) rp1[base + 3] = excl + a0 + a1 + a2 + a3;
    if (t == 255) bsum[blockIdx.x] = sh[255];
}

__global__ void scan_bsum_kernel(int* __restrict__ bsum, int B) {
    __shared__ int sh[256];
    int t = threadIdx.x;
    int run = 0;
    for (int base = 0; base < B; base += 256) {
        int v = (base + t < B) ? bsum[base + t] : 0;
        __syncthreads();
        sh[t] = v; __syncthreads();
        for (int d = 1; d < 256; d <<= 1) {
            int u = (t >= d) ? sh[t - d] : 0;
            __syncthreads();
            sh[t] += u;
            __syncthreads();
        }
        if (base + t < B) bsum[base + t] = run + sh[t] - v;   // exclusive
        run += sh[255];
        __syncthreads();
    }
}

__global__ void add_off_kernel(int* __restrict__ rp1, const int* __restrict__ bsum,
                               int* __restrict__ rowptr0, int N) {
    int t = threadIdx.x;
    int base = blockIdx.x * 1024 + t * 4;
    int off = bsum[blockIdx.x];
#pragma unroll
    for (int j = 0; j < 4; j++)
        if (base + j < N) rp1[base + j] += off;
    if (blockIdx.x == 0 && t == 0) rowptr0[0] = 0;
}

__global__ void copy_kernel(const int* __restrict__ a, int* __restrict__ b, int N) {
    int i = blockIdx.x * blockDim.x + threadIdx.x;
    int stride = gridDim.x * blockDim.x;
    for (; i < N; i += stride) b[i] = a[i];
}

// ---------------- bucket edges by dst ----------------

__global__ void build_csr_kernel(const int* __restrict__ src, const int* __restrict__ dst,
                                 int* __restrict__ cursor, int* __restrict__ es, int E) {
    int i = blockIdx.x * blockDim.x + threadIdx.x;
    int stride = gridDim.x * blockDim.x;
    for (; i < E; i += stride) {
        int pos = atomicAdd(&cursor[dst[i]], 1);
        es[pos] = src[i];
    }
}

// ---------------- fused APPNP pull step ----------------
// one 64-lane wave per dst node. Edges processed in PAIRS: lanes 0-31 gather
// edge A's row as float4, lanes 32-63 edge B's row. Cross-half shfl_xor(32)
// combines the two partial sums at the end.

__global__ __launch_bounds__(256) void pull_kernel(
        const int* __restrict__ rowptr, const int* __restrict__ es,
        const float* __restrict__ dinv, const float* __restrict__ hin,
        const float* __restrict__ x, float* __restrict__ hout, int N) {
    int wid = threadIdx.x >> 6;
    int lane = threadIdx.x & 63;
    int half = lane >> 5;        // which edge of the pair this lane serves
    int l32 = lane & 31;         // float4 slot within the 128-dim row
    int node = blockIdx.x * 4 + wid;
    if (node >= N) return;
    int beg = rowptr[node], end = rowptr[node + 1];
    float dd = dinv[node];
    float4 acc = make_float4(0.f, 0.f, 0.f, 0.f);
    int deg = end - beg;
    for (int base = 0; base < deg; base += 64) {
        int myi = base + lane;
        int msrc = (myi < deg) ? es[beg + myi] : 0;
        float mns = (myi < deg) ? dinv[msrc] * dd : 0.f;
        int cnt = min(64, deg - base);
        int pairs = (cnt + 1) >> 1;
        for (int j = 0; j < pairs; j++) {
            int idx = 2 * j + half;          // staged slot this half consumes
            int s = __shfl(msrc, idx);
            float ns = __shfl(mns, idx);
            float4 v = *((const float4*)(hin + (size_t)s * DIN) + l32);
            acc.x = fmaf(ns, v.x, acc.x);
            acc.y = fmaf(ns, v.y, acc.y);
            acc.z = fmaf(ns, v.z, acc.z);
            acc.w = fmaf(ns, v.w, acc.w);
        }
    }
    // combine the two halves
    acc.x += __shfl_xor(acc.x, 32);
    acc.y += __shfl_xor(acc.y, 32);
    acc.z += __shfl_xor(acc.z, 32);
    acc.w += __shfl_xor(acc.w, 32);
    if (half == 0) {
        float4 hv = *((const float4*)(hin + (size_t)node * DIN) + l32);
        float4 xv = *((const float4*)(x + (size_t)node * DIN) + l32);
        float d2 = dd * dd;
        float4 o;
        o.x = 0.9f * (acc.x + d2 * hv.x) + 0.1f * xv.x;
        o.y = 0.9f * (acc.y + d2 * hv.y) + 0.1f * xv.y;
        o.z = 0.9f * (acc.z + d2 * hv.z) + 0.1f * xv.z;
        o.w = 0.9f * (acc.w + d2 * hv.w) + 0.1f * xv.w;
        *((float4*)(hout + (size_t)node * DIN) + l32) = o;
    }
}

// ---------------- FC1: h2 = relu(h @ W1 + b1), 16 rows/block ----------------

__global__ __launch_bounds__(256) void fc1_kernel(
        const float* __restrict__ h, const float* __restrict__ W,
        const float* __restrict__ b, float* __restrict__ out, int N) {
    __shared__ float sW[DIN * NEU];   // 32 KB
    __shared__ float sh[16][DIN];     // 8 KB
    int tid = threadIdx.x;
    for (int k = tid; k < DIN * NEU; k += 256) sW[k] = W[k];
    int n0 = blockIdx.x * 16;
    for (int k = tid; k < 16 * DIN; k += 256) {
        int r = k >> 7, c = k & 127;
        int n = n0 + r;
        sh[r][c] = (n < N) ? h[(size_t)n * DIN + c] : 0.f;
    }
    __syncthreads();
    int j = tid & 63, r0 = tid >> 6;
    float bj = b[j];
    for (int rr = r0; rr < 16; rr += 4) {
        int n = n0 + rr;
        if (n < N) {
            float acc = bj;
#pragma unroll
            for (int k = 0; k < DIN; k++) acc = fmaf(sh[rr][k], sW[k * NEU + j], acc);
            out[(size_t)n * NEU + j] = fmaxf(acc, 0.f);
        }
    }
}

// ---------------- closeness logits ----------------

__global__ void logits_kernel(const float* __restrict__ cf, const float* __restrict__ cw,
                              const float* __restrict__ cb, float* __restrict__ logits, int N) {
    int i = blockIdx.x * blockDim.x + threadIdx.x;
    if (i >= N) return;
    const float4* c = (const float4*)(cf + (size_t)i * 8);
    float4 a = c[0], b = c[1];
    float s = a.x * cw[0] + a.y * cw[1] + a.z * cw[2] + a.w * cw[3]
            + b.x * cw[4] + b.y * cw[5] + b.z * cw[6] + b.w * cw[7] + cb[0];
    logits[i] = s;
}

// ---------------- per-graph offsets via binary search (batch sorted) ----------------

__global__ void boundary_kernel(const int* __restrict__ batch, int* __restrict__ offs,
                                int N, int G) {
    int g = blockIdx.x * blockDim.x + threadIdx.x;   // 0..G inclusive
    if (g > G) return;
    int lo = 0, hi = N;
    while (lo < hi) {
        int mid = (lo + hi) >> 1;
        if (batch[mid] < g) lo = mid + 1; else hi = mid;
    }
    offs[g] = lo;
}

// ---------------- segment softmax -> p (scaled by count) ----------------

__global__ __launch_bounds__(256) void softmax_kernel(
        const float* __restrict__ logits, const int* __restrict__ offs,
        float* __restrict__ p, int G) {
    int g = blockIdx.x;
    int s0 = offs[g], e0 = offs[g + 1];
    int tid = threadIdx.x;
    __shared__ float red[256];
    float m = -INFINITY;
    for (int i = s0 + tid; i < e0; i += 256) m = fmaxf(m, logits[i]);
    red[tid] = m; __syncthreads();
    for (int w = 128; w > 0; w >>= 1) {
        if (tid < w) red[tid] = fmaxf(red[tid], red[tid + w]);
        __syncthreads();
    }
    m = red[0]; __syncthreads();
    float z = 0.f;
    for (int i = s0 + tid; i < e0; i += 256) z += expf(logits[i] - m);
    red[tid] = z; __syncthreads();
    for (int w = 128; w > 0; w >>= 1) {
        if (tid < w) red[tid] += red[tid + w];
        __syncthreads();
    }
    z = red[0];
    float scale = (float)(e0 - s0) / z;
    for (int i = s0 + tid; i < e0; i += 256) p[i] = expf(logits[i] - m) * scale;
}

// ---------------- weighted segment max-pool ----------------

__global__ __launch_bounds__(256) void pool_kernel(
        const float* __restrict__ h2, const float* __restrict__ p,
        const int* __restrict__ offs, float* __restrict__ pooled, int G) {
    int g = blockIdx.x;
    int s0 = offs[g], e0 = offs[g + 1];
    int tid = threadIdx.x;
    int j = tid & 63, r = tid >> 6;
    float mx = -INFINITY;
    for (int i = s0 + r; i < e0; i += 4)
        mx = fmaxf(mx, p[i] * h2[(size_t)i * NEU + j]);
    __shared__ float red[256];
    red[tid] = mx;
    __syncthreads();
    if (r == 0) {
        float m0 = fmaxf(fmaxf(red[j], red[64 + j]), fmaxf(red[128 + j], red[192 + j]));
        pooled[(size_t)g * NEU + j] = m0;
    }
}

// ---------------- final MLP 64->16->1 ----------------

__global__ void final_kernel(const float* __restrict__ pooled, const float* __restrict__ w1,
                             const float* __restrict__ b1, const float* __restrict__ w2,
                             const float* __restrict__ b2, float* __restrict__ out, int G) {
    int g = blockIdx.x;
    int tid = threadIdx.x;   // 64 threads
    __shared__ float sp[64];
    __shared__ float sa[16];
    sp[tid] = pooled[(size_t)g * 64 + tid];
    __syncthreads();
    if (tid < 16) {
        float acc = b1[tid];
#pragma unroll
        for (int k = 0; k < 64; k++) acc = fmaf(sp[k], w1[k * 16 + tid], acc);
        sa[tid] = fmaxf(acc, 0.f);
    }
    __syncthreads();
    if (tid == 0) {
        float o = b2[0];
#pragma unroll
        for (int k = 0; k < 16; k++) o = fmaf(sa[k], w2[k], o);
        out[g] = o;
    }
}

// ---------------------------------------------------------------------------

extern "C" void kernel_launch(void* const* d_in, const int* in_sizes, int n_in,
                              void* d_out, int out_size, void* d_ws, size_t ws_size,
                              hipStream_t stream) {
    const float* x       = (const float*)d_in[0];
    const float* cf      = (const float*)d_in[1];
    const int*   ei      = (const int*)d_in[2];
    const int*   batch   = (const int*)d_in[3];
    const float* nn1_w   = (const float*)d_in[5];
    const float* nn1_b   = (const float*)d_in[6];
    const float* close_w = (const float*)d_in[7];
    const float* close_b = (const float*)d_in[8];
    const float* att1_w  = (const float*)d_in[9];
    const float* att1_b  = (const float*)d_in[10];
    const float* att2_w  = (const float*)d_in[11];
    const float* att2_b  = (const float*)d_in[12];
    float* out = (float*)d_out;

    int N = in_sizes[0] / DIN;
    int E = in_sizes[2] / 2;
    int G = out_size;

    const int* src = ei;
    const int* dst = ei + E;

    char* w = (char*)d_ws;
    size_t off = 0;
    auto alloc = [&](size_t bytes) -> void* {
        void* ptr = w + off;
        off += (bytes + 511) & ~(size_t)511;
        return ptr;
    };
    float* bufA   = (float*)alloc((size_t)N * DIN * 4);
    float* bufB   = (float*)alloc((size_t)N * DIN * 4);
    float* dinv   = (float*)alloc((size_t)N * 4);
    int*   ncnt   = (int*)alloc((size_t)N * 4);
    int*   rowptr = (int*)alloc(((size_t)N + 1) * 4);
    int*   cursor = (int*)alloc((size_t)N * 4);
    int*   bsum   = (int*)alloc(512 * 4);
    int*   es     = (int*)alloc((size_t)E * 4);
    float* h2     = (float*)alloc((size_t)N * NEU * 4);
    float* logits = (float*)alloc((size_t)N * 4);
    float* p      = (float*)alloc((size_t)N * 4);
    int*   offs   = (int*)alloc(((size_t)G + 1) * 4);
    float* pooled = (float*)alloc((size_t)G * NEU * 4);
    (void)ws_size; (void)n_in;

    int B = (N + 1023) / 1024;

    hipMemsetAsync(ncnt, 0, (size_t)N * 4, stream);

    // --- CSR build ---
    hist_kernel<<<2048, 256, 0, stream>>>(dst, ncnt, E);
    dinv_kernel<<<(N + 255) / 256, 256, 0, stream>>>(ncnt, dinv, N);
    scan_chunk_kernel<<<B, 256, 0, stream>>>(ncnt, rowptr + 1, bsum, N);
    scan_bsum_kernel<<<1, 256, 0, stream>>>(bsum, B);
    add_off_kernel<<<B, 256, 0, stream>>>(rowptr + 1, bsum, rowptr, N);
    copy_kernel<<<2048, 256, 0, stream>>>(rowptr, cursor, N);
    build_csr_kernel<<<2048, 256, 0, stream>>>(src, dst, cursor, es, E);

    // --- APPNP: 3 fused pull+combine steps ---
    pull_kernel<<<(N + 3) / 4, 256, 0, stream>>>(rowptr, es, dinv, x,    x, bufB, N);
    pull_kernel<<<(N + 3) / 4, 256, 0, stream>>>(rowptr, es, dinv, bufB, x, bufA, N);
    pull_kernel<<<(N + 3) / 4, 256, 0, stream>>>(rowptr, es, dinv, bufA, x, bufB, N);

    // --- head ---
    fc1_kernel<<<(N + 15) / 16, 256, 0, stream>>>(bufB, nn1_w, nn1_b, h2, N);
    logits_kernel<<<(N + 255) / 256, 256, 0, stream>>>(cf, close_w, close_b, logits, N);
    boundary_kernel<<<2, 256, 0, stream>>>(batch, offs, N, G);
    softmax_kernel<<<G, 256, 0, stream>>>(logits, offs, p, G);
    pool_kernel<<<G, 256, 0, stream>>>(h2, p, offs, pooled, G);
    final_kernel<<<G, 64, 0, stream>>>(pooled, att1_w, att1_b, att2_w, att2_b, out, G);
}

// Round 4
// 624.445 us; speedup vs baseline: 7.0460x; 1.1146x over previous
//
#include <hip/hip_runtime.h>
#include <cstdint>
#include <cstddef>

// ---------------------------------------------------------------------------
// APPNPNet_Structural: APPNP (K=3) -> FC(128->64)+ReLU -> per-graph softmax
// pooling (weighted segment-max) -> MLP(64->16->1).
// Round 4: packed (src,norm) int2 CSR (no per-edge dinv gather in pull);
//          dual-accumulator unrolled pull; fc1 32 rows/block wave-row-grouped.
// ---------------------------------------------------------------------------

#define DIN 128
#define NEU 64

// ---------------- degree histogram (int) ----------------

__global__ void hist_kernel(const int* __restrict__ dst, int* __restrict__ cnt, int E) {
    int i = blockIdx.x * blockDim.x + threadIdx.x;
    int stride = gridDim.x * blockDim.x;
    for (; i < E; i += stride) atomicAdd(&cnt[dst[i]], 1);
}

__global__ void dinv_kernel(const int* __restrict__ cnt, float* __restrict__ dinv, int N) {
    int i = blockIdx.x * blockDim.x + threadIdx.x;
    if (i < N) dinv[i] = rsqrtf((float)cnt[i] + 1.0f);   // +1 = self loop
}

// ---------------- 3-kernel prefix scan of cnt[N] -> rowptr[N+1] ----------------

__global__ void scan_chunk_kernel(const int* __restrict__ cnt, int* __restrict__ rp1,
                                  int* __restrict__ bsum, int N) {
    __shared__ int sh[256];
    int t = threadIdx.x;
    int base = blockIdx.x * 1024 + t * 4;
    int a0 = (base + 0 < N) ? cnt[base + 0] : 0;
    int a1 = (base + 1 < N) ? cnt[base + 1] : 0;
    int a2 = (base + 2 < N) ? cnt[base + 2] : 0;
    int a3 = (base + 3 < N) ? cnt[base + 3] : 0;
    int s = a0 + a1 + a2 + a3;
    sh[t] = s; __syncthreads();
    for (int d = 1; d < 256; d <<= 1) {
        int v = (t >= d) ? sh[t - d] : 0;
        __syncthreads();
        sh[t] += v;
        __syncthreads();
    }
    int excl = sh[t] - s;
    if (base + 0 < N) rp1[base + 0] = excl + a0;
    if (base + 1 < N) rp1[base + 1] = excl + a0 + a1;
    if (base + 2 < N) rp1[base + 2] = excl + a0 + a1 + a2;
    if (base + 3 < N) rp1[base + 3] = excl + a0 + a1 + a2 + a3;
    if (t == 255) bsum[blockIdx.x] = sh[255];
}

__global__ void scan_bsum_kernel(int* __restrict__ bsum, int B) {
    __shared__ int sh[256];
    int t = threadIdx.x;
    int run = 0;
    for (int base = 0; base < B; base += 256) {
        int v = (base + t < B) ? bsum[base + t] : 0;
        __syncthreads();
        sh[t] = v; __syncthreads();
        for (int d = 1; d < 256; d <<= 1) {
            int u = (t >= d) ? sh[t - d] : 0;
            __syncthreads();
            sh[t] += u;
            __syncthreads();
        }
        if (base + t < B) bsum[base + t] = run + sh[t] - v;   // exclusive
        run += sh[255];
        __syncthreads();
    }
}

// rowptr finalize + cursor init (fused old copy_kernel)
__global__ void add_off_kernel(int* __restrict__ rp1, const int* __restrict__ bsum,
                               int* __restrict__ rowptr0, int* __restrict__ cursor, int N) {
    int t = threadIdx.x;
    int base = blockIdx.x * 1024 + t * 4;
    int off = bsum[blockIdx.x];
#pragma unroll
    for (int j = 0; j < 4; j++) {
        int idx = base + j;
        if (idx < N) {
            int v = rp1[idx] + off;
            rp1[idx] = v;                 // rowptr[idx+1]
            if (idx + 1 < N) cursor[idx + 1] = v;
        }
    }
    if (blockIdx.x == 0 && t == 0) { rowptr0[0] = 0; cursor[0] = 0; }
}

// ---------------- bucket edges by dst, packing (src, norm) ----------------

__global__ void build_csr_kernel(const int* __restrict__ src, const int* __restrict__ dst,
                                 const float* __restrict__ dinv,
                                 int* __restrict__ cursor, int2* __restrict__ es2, int E) {
    int i = blockIdx.x * blockDim.x + threadIdx.x;
    int stride = gridDim.x * blockDim.x;
    for (; i < E; i += stride) {
        int s = src[i], d = dst[i];
        float nm = dinv[s] * dinv[d];
        int pos = atomicAdd(&cursor[d], 1);
        es2[pos] = make_int2(s, __float_as_int(nm));
    }
}

// ---------------- fused APPNP pull step ----------------
// one 64-lane wave per dst node. Edges in PAIRS (lanes 0-31 edge A as float4,
// lanes 32-63 edge B), unrolled x2 with dual accumulators for MLP.

__global__ __launch_bounds__(256) void pull_kernel(
        const int* __restrict__ rowptr, const int2* __restrict__ es2,
        const float* __restrict__ dinv, const float* __restrict__ hin,
        const float* __restrict__ x, float* __restrict__ hout, int N) {
    int wid = threadIdx.x >> 6;
    int lane = threadIdx.x & 63;
    int half = lane >> 5;
    int l32 = lane & 31;
    int node = blockIdx.x * 4 + wid;
    if (node >= N) return;
    int beg = rowptr[node], end = rowptr[node + 1];
    float dd = dinv[node];
    float4 acc0 = make_float4(0.f, 0.f, 0.f, 0.f);
    float4 acc1 = make_float4(0.f, 0.f, 0.f, 0.f);
    int deg = end - beg;
    for (int base = 0; base < deg; base += 64) {
        int myi = base + lane;
        int2 e = (myi < deg) ? es2[beg + myi] : make_int2(0, 0);
        int msrc = e.x;
        float mns = __int_as_float(e.y);
        int cnt = min(64, deg - base);
        int pairs = (cnt + 1) >> 1;
        int j = 0;
        for (; j + 1 < pairs; j += 2) {
            int i0 = 2 * j + half;
            int i1 = 2 * j + 2 + half;
            int s0 = __shfl(msrc, i0);
            float n0 = __shfl(mns, i0);
            int s1 = __shfl(msrc, i1);
            float n1 = __shfl(mns, i1);
            float4 v0 = *((const float4*)(hin + (size_t)s0 * DIN) + l32);
            float4 v1 = *((const float4*)(hin + (size_t)s1 * DIN) + l32);
            acc0.x = fmaf(n0, v0.x, acc0.x);
            acc0.y = fmaf(n0, v0.y, acc0.y);
            acc0.z = fmaf(n0, v0.z, acc0.z);
            acc0.w = fmaf(n0, v0.w, acc0.w);
            acc1.x = fmaf(n1, v1.x, acc1.x);
            acc1.y = fmaf(n1, v1.y, acc1.y);
            acc1.z = fmaf(n1, v1.z, acc1.z);
            acc1.w = fmaf(n1, v1.w, acc1.w);
        }
        if (j < pairs) {
            int i0 = 2 * j + half;
            int s0 = __shfl(msrc, i0);
            float n0 = __shfl(mns, i0);
            float4 v0 = *((const float4*)(hin + (size_t)s0 * DIN) + l32);
            acc0.x = fmaf(n0, v0.x, acc0.x);
            acc0.y = fmaf(n0, v0.y, acc0.y);
            acc0.z = fmaf(n0, v0.z, acc0.z);
            acc0.w = fmaf(n0, v0.w, acc0.w);
        }
    }
    float4 acc;
    acc.x = acc0.x + acc1.x;
    acc.y = acc0.y + acc1.y;
    acc.z = acc0.z + acc1.z;
    acc.w = acc0.w + acc1.w;
    acc.x += __shfl_xor(acc.x, 32);
    acc.y += __shfl_xor(acc.y, 32);
    acc.z += __shfl_xor(acc.z, 32);
    acc.w += __shfl_xor(acc.w, 32);
    if (half == 0) {
        float4 hv = *((const float4*)(hin + (size_t)node * DIN) + l32);
        float4 xv = *((const float4*)(x + (size_t)node * DIN) + l32);
        float d2 = dd * dd;
        float4 o;
        o.x = 0.9f * (acc.x + d2 * hv.x) + 0.1f * xv.x;
        o.y = 0.9f * (acc.y + d2 * hv.y) + 0.1f * xv.y;
        o.z = 0.9f * (acc.z + d2 * hv.z) + 0.1f * xv.z;
        o.w = 0.9f * (acc.w + d2 * hv.w) + 0.1f * xv.w;
        *((float4*)(hout + (size_t)node * DIN) + l32) = o;
    }
}

// ---------------- FC1: 32 rows/block, wave owns 8 rows ----------------
// per k: 1 sW read (2-way bank, free) + 8 wave-uniform broadcasts -> 8 FMA.

__global__ __launch_bounds__(256) void fc1_kernel(
        const float* __restrict__ h, const float* __restrict__ W,
        const float* __restrict__ b, float* __restrict__ out, int N) {
    __shared__ float sW[DIN * NEU];   // 32 KB
    __shared__ float sh[32][DIN];     // 16 KB
    int tid = threadIdx.x;
    for (int k = tid; k < DIN * NEU; k += 256) sW[k] = W[k];
    int n0 = blockIdx.x * 32;
    for (int q = tid; q < 32 * 32; q += 256) {      // 32 rows x 32 float4
        int r = q >> 5, c4 = q & 31;
        int n = n0 + r;
        float4 v = (n < N) ? *((const float4*)(h + (size_t)n * DIN) + c4)
                           : make_float4(0.f, 0.f, 0.f, 0.f);
        *((float4*)&sh[r][0] + c4) = v;
    }
    __syncthreads();
    int j = tid & 63, wv = tid >> 6;
    int r0 = wv * 8;
    float bj = b[j];
    float acc[8];
#pragma unroll
    for (int r = 0; r < 8; r++) acc[r] = bj;
#pragma unroll 4
    for (int k = 0; k < DIN; k++) {
        float wk = sW[k * NEU + j];
#pragma unroll
        for (int r = 0; r < 8; r++) acc[r] = fmaf(sh[r0 + r][k], wk, acc[r]);
    }
#pragma unroll
    for (int r = 0; r < 8; r++) {
        int n = n0 + r0 + r;
        if (n < N) out[(size_t)n * NEU + j] = fmaxf(acc[r], 0.f);
    }
}

// ---------------- closeness logits ----------------

__global__ void logits_kernel(const float* __restrict__ cf, const float* __restrict__ cw,
                              const float* __restrict__ cb, float* __restrict__ logits, int N) {
    int i = blockIdx.x * blockDim.x + threadIdx.x;
    if (i >= N) return;
    const float4* c = (const float4*)(cf + (size_t)i * 8);
    float4 a = c[0], b = c[1];
    float s = a.x * cw[0] + a.y * cw[1] + a.z * cw[2] + a.w * cw[3]
            + b.x * cw[4] + b.y * cw[5] + b.z * cw[6] + b.w * cw[7] + cb[0];
    logits[i] = s;
}

// ---------------- per-graph offsets via binary search (batch sorted) ----------------

__global__ void boundary_kernel(const int* __restrict__ batch, int* __restrict__ offs,
                                int N, int G) {
    int g = blockIdx.x * blockDim.x + threadIdx.x;   // 0..G inclusive
    if (g > G) return;
    int lo = 0, hi = N;
    while (lo < hi) {
        int mid = (lo + hi) >> 1;
        if (batch[mid] < g) lo = mid + 1; else hi = mid;
    }
    offs[g] = lo;
}

// ---------------- segment softmax -> p (scaled by count) ----------------

__global__ __launch_bounds__(256) void softmax_kernel(
        const float* __restrict__ logits, const int* __restrict__ offs,
        float* __restrict__ p, int G) {
    int g = blockIdx.x;
    int s0 = offs[g], e0 = offs[g + 1];
    int tid = threadIdx.x;
    __shared__ float red[256];
    float m = -INFINITY;
    for (int i = s0 + tid; i < e0; i += 256) m = fmaxf(m, logits[i]);
    red[tid] = m; __syncthreads();
    for (int w = 128; w > 0; w >>= 1) {
        if (tid < w) red[tid] = fmaxf(red[tid], red[tid + w]);
        __syncthreads();
    }
    m = red[0]; __syncthreads();
    float z = 0.f;
    for (int i = s0 + tid; i < e0; i += 256) z += expf(logits[i] - m);
    red[tid] = z; __syncthreads();
    for (int w = 128; w > 0; w >>= 1) {
        if (tid < w) red[tid] += red[tid + w];
        __syncthreads();
    }
    z = red[0];
    float scale = (float)(e0 - s0) / z;
    for (int i = s0 + tid; i < e0; i += 256) p[i] = expf(logits[i] - m) * scale;
}

// ---------------- weighted segment max-pool ----------------

__global__ __launch_bounds__(256) void pool_kernel(
        const float* __restrict__ h2, const float* __restrict__ p,
        const int* __restrict__ offs, float* __restrict__ pooled, int G) {
    int g = blockIdx.x;
    int s0 = offs[g], e0 = offs[g + 1];
    int tid = threadIdx.x;
    int j = tid & 63, r = tid >> 6;
    float mx = -INFINITY;
    for (int i = s0 + r; i < e0; i += 4)
        mx = fmaxf(mx, p[i] * h2[(size_t)i * NEU + j]);
    __shared__ float red[256];
    red[tid] = mx;
    __syncthreads();
    if (r == 0) {
        float m0 = fmaxf(fmaxf(red[j], red[64 + j]), fmaxf(red[128 + j], red[192 + j]));
        pooled[(size_t)g * NEU + j] = m0;
    }
}

// ---------------- final MLP 64->16->1 ----------------

__global__ void final_kernel(const float* __restrict__ pooled, const float* __restrict__ w1,
                             const float* __restrict__ b1, const float* __restrict__ w2,
                             const float* __restrict__ b2, float* __restrict__ out, int G) {
    int g = blockIdx.x;
    int tid = threadIdx.x;   // 64 threads
    __shared__ float sp[64];
    __shared__ float sa[16];
    sp[tid] = pooled[(size_t)g * 64 + tid];
    __syncthreads();
    if (tid < 16) {
        float acc = b1[tid];
#pragma unroll
        for (int k = 0; k < 64; k++) acc = fmaf(sp[k], w1[k * 16 + tid], acc);
        sa[tid] = fmaxf(acc, 0.f);
    }
    __syncthreads();
    if (tid == 0) {
        float o = b2[0];
#pragma unroll
        for (int k = 0; k < 16; k++) o = fmaf(sa[k], w2[k], o);
        out[g] = o;
    }
}

// ---------------------------------------------------------------------------

extern "C" void kernel_launch(void* const* d_in, const int* in_sizes, int n_in,
                              void* d_out, int out_size, void* d_ws, size_t ws_size,
                              hipStream_t stream) {
    const float* x       = (const float*)d_in[0];
    const float* cf      = (const float*)d_in[1];
    const int*   ei      = (const int*)d_in[2];
    const int*   batch   = (const int*)d_in[3];
    const float* nn1_w   = (const float*)d_in[5];
    const float* nn1_b   = (const float*)d_in[6];
    const float* close_w = (const float*)d_in[7];
    const float* close_b = (const float*)d_in[8];
    const float* att1_w  = (const float*)d_in[9];
    const float* att1_b  = (const float*)d_in[10];
    const float* att2_w  = (const float*)d_in[11];
    const float* att2_b  = (const float*)d_in[12];
    float* out = (float*)d_out;

    int N = in_sizes[0] / DIN;
    int E = in_sizes[2] / 2;
    int G = out_size;

    const int* src = ei;
    const int* dst = ei + E;

    char* w = (char*)d_ws;
    size_t off = 0;
    auto alloc = [&](size_t bytes) -> void* {
        void* ptr = w + off;
        off += (bytes + 511) & ~(size_t)511;
        return ptr;
    };
    float* bufA   = (float*)alloc((size_t)N * DIN * 4);
    float* bufB   = (float*)alloc((size_t)N * DIN * 4);
    float* dinv   = (float*)alloc((size_t)N * 4);
    int*   ncnt   = (int*)alloc((size_t)N * 4);
    int*   rowptr = (int*)alloc(((size_t)N + 1) * 4);
    int*   cursor = (int*)alloc((size_t)N * 4);
    int*   bsum   = (int*)alloc(512 * 4);
    int2*  es2    = (int2*)alloc((size_t)E * 8);
    float* h2     = (float*)alloc((size_t)N * NEU * 4);
    float* logits = (float*)alloc((size_t)N * 4);
    float* p      = (float*)alloc((size_t)N * 4);
    int*   offs   = (int*)alloc(((size_t)G + 1) * 4);
    float* pooled = (float*)alloc((size_t)G * NEU * 4);
    (void)ws_size; (void)n_in;

    int B = (N + 1023) / 1024;

    hipMemsetAsync(ncnt, 0, (size_t)N * 4, stream);

    // --- CSR build ---
    hist_kernel<<<2048, 256, 0, stream>>>(dst, ncnt, E);
    dinv_kernel<<<(N + 255) / 256, 256, 0, stream>>>(ncnt, dinv, N);
    scan_chunk_kernel<<<B, 256, 0, stream>>>(ncnt, rowptr + 1, bsum, N);
    scan_bsum_kernel<<<1, 256, 0, stream>>>(bsum, B);
    add_off_kernel<<<B, 256, 0, stream>>>(rowptr + 1, bsum, rowptr, cursor, N);
    build_csr_kernel<<<2048, 256, 0, stream>>>(src, dst, dinv, cursor, es2, E);

    // --- APPNP: 3 fused pull+combine steps ---
    pull_kernel<<<(N + 3) / 4, 256, 0, stream>>>(rowptr, es2, dinv, x,    x, bufB, N);
    pull_kernel<<<(N + 3) / 4, 256, 0, stream>>>(rowptr, es2, dinv, bufB, x, bufA, N);
    pull_kernel<<<(N + 3) / 4, 256, 0, stream>>>(rowptr, es2, dinv, bufA, x, bufB, N);

    // --- head ---
    fc1_kernel<<<(N + 31) / 32, 256, 0, stream>>>(bufB, nn1_w, nn1_b, h2, N);
    logits_kernel<<<(N + 255) / 256, 256, 0, stream>>>(cf, close_w, close_b, logits, N);
    boundary_kernel<<<2, 256, 0, stream>>>(batch, offs, N, G);
    softmax_kernel<<<G, 256, 0, stream>>>(logits, offs, p, G);
    pool_kernel<<<G, 256, 0, stream>>>(h2, p, offs, pooled, G);
    final_kernel<<<G, 64, 0, stream>>>(pooled, att1_w, att1_b, att2_w, att2_b, out, G);
}

// Round 5
// 470.317 us; speedup vs baseline: 9.3550x; 1.3277x over previous
//
#include <hip/hip_runtime.h>
#include <cstdint>
#include <cstddef>

// ---------------------------------------------------------------------------
// APPNPNet_Structural: APPNP (K=3) -> FC(128->64)+ReLU -> per-graph softmax
// pooling (weighted segment-max) -> MLP(64->16->1).
// Round 5: bf16 storage for propagated rows (halves gather bytes — pull was
// exactly at the 6.3 TB/s gather roofline at f32). f32 accumulation, RNE
// stores. fc1 consumes bf16. Packed (src,norm) CSR unchanged.
// ---------------------------------------------------------------------------

#define DIN 128
#define NEU 64

// bf16 helpers: storage = ushort, math = f32.
__device__ inline float bf2f(unsigned short h) {
    return __uint_as_float(((unsigned)h) << 16);
}
__device__ inline unsigned short f2bf(float f) {   // round-to-nearest-even
    unsigned u = __float_as_uint(f);
    unsigned r = u + 0x7FFFu + ((u >> 16) & 1u);
    return (unsigned short)(r >> 16);
}
__device__ inline float bflo(unsigned u) { return __uint_as_float(u << 16); }
__device__ inline float bfhi(unsigned u) { return __uint_as_float(u & 0xFFFF0000u); }

// ---------------- f32 -> bf16 conversion (x -> xb) ----------------

__global__ void tobf16_kernel(const float* __restrict__ in, ushort* __restrict__ out,
                              int total4) {
    int i = blockIdx.x * blockDim.x + threadIdx.x;
    int stride = gridDim.x * blockDim.x;
    for (; i < total4; i += stride) {
        float4 v = ((const float4*)in)[i];
        ushort4 o;
        o.x = f2bf(v.x); o.y = f2bf(v.y); o.z = f2bf(v.z); o.w = f2bf(v.w);
        ((ushort4*)out)[i] = o;
    }
}

// ---------------- degree histogram (int) ----------------

__global__ void hist_kernel(const int* __restrict__ dst, int* __restrict__ cnt, int E) {
    int i = blockIdx.x * blockDim.x + threadIdx.x;
    int stride = gridDim.x * blockDim.x;
    for (; i < E; i += stride) atomicAdd(&cnt[dst[i]], 1);
}

__global__ void dinv_kernel(const int* __restrict__ cnt, float* __restrict__ dinv, int N) {
    int i = blockIdx.x * blockDim.x + threadIdx.x;
    if (i < N) dinv[i] = rsqrtf((float)cnt[i] + 1.0f);   // +1 = self loop
}

// ---------------- 3-kernel prefix scan of cnt[N] -> rowptr[N+1] ----------------

__global__ void scan_chunk_kernel(const int* __restrict__ cnt, int* __restrict__ rp1,
                                  int* __restrict__ bsum, int N) {
    __shared__ int sh[256];
    int t = threadIdx.x;
    int base = blockIdx.x * 1024 + t * 4;
    int a0 = (base + 0 < N) ? cnt[base + 0] : 0;
    int a1 = (base + 1 < N) ? cnt[base + 1] : 0;
    int a2 = (base + 2 < N) ? cnt[base + 2] : 0;
    int a3 = (base + 3 < N) ? cnt[base + 3] : 0;
    int s = a0 + a1 + a2 + a3;
    sh[t] = s; __syncthreads();
    for (int d = 1; d < 256; d <<= 1) {
        int v = (t >= d) ? sh[t - d] : 0;
        __syncthreads();
        sh[t] += v;
        __syncthreads();
    }
    int excl = sh[t] - s;
    if (base + 0 < N) rp1[base + 0] = excl + a0;
    if (base + 1 < N) rp1[base + 1] = excl + a0 + a1;
    if (base + 2 < N) rp1[base + 2] = excl + a0 + a1 + a2;
    if (base + 3 < N) rp1[base + 3] = excl + a0 + a1 + a2 + a3;
    if (t == 255) bsum[blockIdx.x] = sh[255];
}

__global__ void scan_bsum_kernel(int* __restrict__ bsum, int B) {
    __shared__ int sh[256];
    int t = threadIdx.x;
    int run = 0;
    for (int base = 0; base < B; base += 256) {
        int v = (base + t < B) ? bsum[base + t] : 0;
        __syncthreads();
        sh[t] = v; __syncthreads();
        for (int d = 1; d < 256; d <<= 1) {
            int u = (t >= d) ? sh[t - d] : 0;
            __syncthreads();
            sh[t] += u;
            __syncthreads();
        }
        if (base + t < B) bsum[base + t] = run + sh[t] - v;   // exclusive
        run += sh[255];
        __syncthreads();
    }
}

// rowptr finalize + cursor init
__global__ void add_off_kernel(int* __restrict__ rp1, const int* __restrict__ bsum,
                               int* __restrict__ rowptr0, int* __restrict__ cursor, int N) {
    int t = threadIdx.x;
    int base = blockIdx.x * 1024 + t * 4;
    int off = bsum[blockIdx.x];
#pragma unroll
    for (int j = 0; j < 4; j++) {
        int idx = base + j;
        if (idx < N) {
            int v = rp1[idx] + off;
            rp1[idx] = v;                 // rowptr[idx+1]
            if (idx + 1 < N) cursor[idx + 1] = v;
        }
    }
    if (blockIdx.x == 0 && t == 0) { rowptr0[0] = 0; cursor[0] = 0; }
}

// ---------------- bucket edges by dst, packing (src, norm) ----------------

__global__ void build_csr_kernel(const int* __restrict__ src, const int* __restrict__ dst,
                                 const float* __restrict__ dinv,
                                 int* __restrict__ cursor, int2* __restrict__ es2, int E) {
    int i = blockIdx.x * blockDim.x + threadIdx.x;
    int stride = gridDim.x * blockDim.x;
    for (; i < E; i += stride) {
        int s = src[i], d = dst[i];
        float nm = dinv[s] * dinv[d];
        int pos = atomicAdd(&cursor[d], 1);
        es2[pos] = make_int2(s, __float_as_int(nm));
    }
}

// ---------------- fused APPNP pull step (bf16 rows) ----------------
// one 64-lane wave per dst node. Edges in PAIRS: lanes 0-31 gather edge A's
// row (ushort4 = 4 bf16 per lane, 256 B/row), lanes 32-63 edge B. f32 accum,
// cross-half shfl_xor(32) combine, bf16 RNE store.

__global__ __launch_bounds__(256) void pull_kernel(
        const int* __restrict__ rowptr, const int2* __restrict__ es2,
        const float* __restrict__ dinv, const ushort* __restrict__ hin,
        const ushort* __restrict__ xb, ushort* __restrict__ hout, int N) {
    int wid = threadIdx.x >> 6;
    int lane = threadIdx.x & 63;
    int half = lane >> 5;
    int l32 = lane & 31;
    int node = blockIdx.x * 4 + wid;
    if (node >= N) return;
    int beg = rowptr[node], end = rowptr[node + 1];
    float dd = dinv[node];
    float4 acc0 = make_float4(0.f, 0.f, 0.f, 0.f);
    float4 acc1 = make_float4(0.f, 0.f, 0.f, 0.f);
    int deg = end - beg;
    for (int base = 0; base < deg; base += 64) {
        int myi = base + lane;
        int2 e = (myi < deg) ? es2[beg + myi] : make_int2(0, 0);
        int msrc = e.x;
        float mns = __int_as_float(e.y);
        int cnt = min(64, deg - base);
        int pairs = (cnt + 1) >> 1;
        int j = 0;
        for (; j + 1 < pairs; j += 2) {
            int i0 = 2 * j + half;
            int i1 = 2 * j + 2 + half;
            int s0 = __shfl(msrc, i0);
            float n0 = __shfl(mns, i0);
            int s1 = __shfl(msrc, i1);
            float n1 = __shfl(mns, i1);
            ushort4 w0 = *((const ushort4*)(hin + (size_t)s0 * DIN) + l32);
            ushort4 w1 = *((const ushort4*)(hin + (size_t)s1 * DIN) + l32);
            acc0.x = fmaf(n0, bf2f(w0.x), acc0.x);
            acc0.y = fmaf(n0, bf2f(w0.y), acc0.y);
            acc0.z = fmaf(n0, bf2f(w0.z), acc0.z);
            acc0.w = fmaf(n0, bf2f(w0.w), acc0.w);
            acc1.x = fmaf(n1, bf2f(w1.x), acc1.x);
            acc1.y = fmaf(n1, bf2f(w1.y), acc1.y);
            acc1.z = fmaf(n1, bf2f(w1.z), acc1.z);
            acc1.w = fmaf(n1, bf2f(w1.w), acc1.w);
        }
        if (j < pairs) {
            int i0 = 2 * j + half;
            int s0 = __shfl(msrc, i0);
            float n0 = __shfl(mns, i0);
            ushort4 w0 = *((const ushort4*)(hin + (size_t)s0 * DIN) + l32);
            acc0.x = fmaf(n0, bf2f(w0.x), acc0.x);
            acc0.y = fmaf(n0, bf2f(w0.y), acc0.y);
            acc0.z = fmaf(n0, bf2f(w0.z), acc0.z);
            acc0.w = fmaf(n0, bf2f(w0.w), acc0.w);
        }
    }
    float4 acc;
    acc.x = acc0.x + acc1.x;
    acc.y = acc0.y + acc1.y;
    acc.z = acc0.z + acc1.z;
    acc.w = acc0.w + acc1.w;
    acc.x += __shfl_xor(acc.x, 32);
    acc.y += __shfl_xor(acc.y, 32);
    acc.z += __shfl_xor(acc.z, 32);
    acc.w += __shfl_xor(acc.w, 32);
    if (half == 0) {
        ushort4 hv = *((const ushort4*)(hin + (size_t)node * DIN) + l32);
        ushort4 xv = *((const ushort4*)(xb + (size_t)node * DIN) + l32);
        float d2 = dd * dd;
        ushort4 o;
        o.x = f2bf(0.9f * (acc.x + d2 * bf2f(hv.x)) + 0.1f * bf2f(xv.x));
        o.y = f2bf(0.9f * (acc.y + d2 * bf2f(hv.y)) + 0.1f * bf2f(xv.y));
        o.z = f2bf(0.9f * (acc.z + d2 * bf2f(hv.z)) + 0.1f * bf2f(xv.z));
        o.w = f2bf(0.9f * (acc.w + d2 * bf2f(hv.w)) + 0.1f * bf2f(xv.w));
        *((ushort4*)(hout + (size_t)node * DIN) + l32) = o;
    }
}

// ---------------- FC1: h2 = relu(h @ W1 + b1), bf16 input, 32 rows/block ----------------

__global__ __launch_bounds__(256) void fc1_kernel(
        const ushort* __restrict__ hb, const float* __restrict__ W,
        const float* __restrict__ b, float* __restrict__ out, int N) {
    __shared__ float sW[DIN * NEU];   // 32 KB
    __shared__ float sh[32][DIN];     // 16 KB
    int tid = threadIdx.x;
    for (int k = tid; k < DIN * NEU; k += 256) sW[k] = W[k];
    int n0 = blockIdx.x * 32;
    for (int q = tid; q < 32 * 16; q += 256) {      // 32 rows x 16 uint4 (8 bf16 each)
        int r = q >> 4, c8 = q & 15;
        int n = n0 + r;
        uint4 v = (n < N) ? *((const uint4*)(hb + (size_t)n * DIN) + c8)
                          : make_uint4(0, 0, 0, 0);
        int c = c8 * 8;
        sh[r][c + 0] = bflo(v.x); sh[r][c + 1] = bfhi(v.x);
        sh[r][c + 2] = bflo(v.y); sh[r][c + 3] = bfhi(v.y);
        sh[r][c + 4] = bflo(v.z); sh[r][c + 5] = bfhi(v.z);
        sh[r][c + 6] = bflo(v.w); sh[r][c + 7] = bfhi(v.w);
    }
    __syncthreads();
    int j = tid & 63, wv = tid >> 6;
    int r0 = wv * 8;
    float bj = b[j];
    float acc[8];
#pragma unroll
    for (int r = 0; r < 8; r++) acc[r] = bj;
#pragma unroll 4
    for (int k = 0; k < DIN; k++) {
        float wk = sW[k * NEU + j];
#pragma unroll
        for (int r = 0; r < 8; r++) acc[r] = fmaf(sh[r0 + r][k], wk, acc[r]);
    }
#pragma unroll
    for (int r = 0; r < 8; r++) {
        int n = n0 + r0 + r;
        if (n < N) out[(size_t)n * NEU + j] = fmaxf(acc[r], 0.f);
    }
}

// ---------------- closeness logits ----------------

__global__ void logits_kernel(const float* __restrict__ cf, const float* __restrict__ cw,
                              const float* __restrict__ cb, float* __restrict__ logits, int N) {
    int i = blockIdx.x * blockDim.x + threadIdx.x;
    if (i >= N) return;
    const float4* c = (const float4*)(cf + (size_t)i * 8);
    float4 a = c[0], b = c[1];
    float s = a.x * cw[0] + a.y * cw[1] + a.z * cw[2] + a.w * cw[3]
            + b.x * cw[4] + b.y * cw[5] + b.z * cw[6] + b.w * cw[7] + cb[0];
    logits[i] = s;
}

// ---------------- per-graph offsets via binary search (batch sorted) ----------------

__global__ void boundary_kernel(const int* __restrict__ batch, int* __restrict__ offs,
                                int N, int G) {
    int g = blockIdx.x * blockDim.x + threadIdx.x;   // 0..G inclusive
    if (g > G) return;
    int lo = 0, hi = N;
    while (lo < hi) {
        int mid = (lo + hi) >> 1;
        if (batch[mid] < g) lo = mid + 1; else hi = mid;
    }
    offs[g] = lo;
}

// ---------------- segment softmax -> p (scaled by count) ----------------

__global__ __launch_bounds__(256) void softmax_kernel(
        const float* __restrict__ logits, const int* __restrict__ offs,
        float* __restrict__ p, int G) {
    int g = blockIdx.x;
    int s0 = offs[g], e0 = offs[g + 1];
    int tid = threadIdx.x;
    __shared__ float red[256];
    float m = -INFINITY;
    for (int i = s0 + tid; i < e0; i += 256) m = fmaxf(m, logits[i]);
    red[tid] = m; __syncthreads();
    for (int w = 128; w > 0; w >>= 1) {
        if (tid < w) red[tid] = fmaxf(red[tid], red[tid + w]);
        __syncthreads();
    }
    m = red[0]; __syncthreads();
    float z = 0.f;
    for (int i = s0 + tid; i < e0; i += 256) z += expf(logits[i] - m);
    red[tid] = z; __syncthreads();
    for (int w = 128; w > 0; w >>= 1) {
        if (tid < w) red[tid] += red[tid + w];
        __syncthreads();
    }
    z = red[0];
    float scale = (float)(e0 - s0) / z;
    for (int i = s0 + tid; i < e0; i += 256) p[i] = expf(logits[i] - m) * scale;
}

// ---------------- weighted segment max-pool ----------------

__global__ __launch_bounds__(256) void pool_kernel(
        const float* __restrict__ h2, const float* __restrict__ p,
        const int* __restrict__ offs, float* __restrict__ pooled, int G) {
    int g = blockIdx.x;
    int s0 = offs[g], e0 = offs[g + 1];
    int tid = threadIdx.x;
    int j = tid & 63, r = tid >> 6;
    float mx = -INFINITY;
    for (int i = s0 + r; i < e0; i += 4)
        mx = fmaxf(mx, p[i] * h2[(size_t)i * NEU + j]);
    __shared__ float red[256];
    red[tid] = mx;
    __syncthreads();
    if (r == 0) {
        float m0 = fmaxf(fmaxf(red[j], red[64 + j]), fmaxf(red[128 + j], red[192 + j]));
        pooled[(size_t)g * NEU + j] = m0;
    }
}

// ---------------- final MLP 64->16->1 ----------------

__global__ void final_kernel(const float* __restrict__ pooled, const float* __restrict__ w1,
                             const float* __restrict__ b1, const float* __restrict__ w2,
                             const float* __restrict__ b2, float* __restrict__ out, int G) {
    int g = blockIdx.x;
    int tid = threadIdx.x;   // 64 threads
    __shared__ float sp[64];
    __shared__ float sa[16];
    sp[tid] = pooled[(size_t)g * 64 + tid];
    __syncthreads();
    if (tid < 16) {
        float acc = b1[tid];
#pragma unroll
        for (int k = 0; k < 64; k++) acc = fmaf(sp[k], w1[k * 16 + tid], acc);
        sa[tid] = fmaxf(acc, 0.f);
    }
    __syncthreads();
    if (tid == 0) {
        float o = b2[0];
#pragma unroll
        for (int k = 0; k < 16; k++) o = fmaf(sa[k], w2[k], o);
        out[g] = o;
    }
}

// ---------------------------------------------------------------------------

extern "C" void kernel_launch(void* const* d_in, const int* in_sizes, int n_in,
                              void* d_out, int out_size, void* d_ws, size_t ws_size,
                              hipStream_t stream) {
    const float* x       = (const float*)d_in[0];
    const float* cf      = (const float*)d_in[1];
    const int*   ei      = (const int*)d_in[2];
    const int*   batch   = (const int*)d_in[3];
    const float* nn1_w   = (const float*)d_in[5];
    const float* nn1_b   = (const float*)d_in[6];
    const float* close_w = (const float*)d_in[7];
    const float* close_b = (const float*)d_in[8];
    const float* att1_w  = (const float*)d_in[9];
    const float* att1_b  = (const float*)d_in[10];
    const float* att2_w  = (const float*)d_in[11];
    const float* att2_b  = (const float*)d_in[12];
    float* out = (float*)d_out;

    int N = in_sizes[0] / DIN;
    int E = in_sizes[2] / 2;
    int G = out_size;

    const int* src = ei;
    const int* dst = ei + E;

    char* w = (char*)d_ws;
    size_t off = 0;
    auto alloc = [&](size_t bytes) -> void* {
        void* ptr = w + off;
        off += (bytes + 511) & ~(size_t)511;
        return ptr;
    };
    ushort* xb     = (ushort*)alloc((size_t)N * DIN * 2);
    ushort* hb0    = (ushort*)alloc((size_t)N * DIN * 2);
    ushort* hb1    = (ushort*)alloc((size_t)N * DIN * 2);
    float* dinv    = (float*)alloc((size_t)N * 4);
    int*   ncnt    = (int*)alloc((size_t)N * 4);
    int*   rowptr  = (int*)alloc(((size_t)N + 1) * 4);
    int*   cursor  = (int*)alloc((size_t)N * 4);
    int*   bsum    = (int*)alloc(512 * 4);
    int2*  es2     = (int2*)alloc((size_t)E * 8);
    float* h2      = (float*)alloc((size_t)N * NEU * 4);
    float* logits  = (float*)alloc((size_t)N * 4);
    float* p       = (float*)alloc((size_t)N * 4);
    int*   offs    = (int*)alloc(((size_t)G + 1) * 4);
    float* pooled  = (float*)alloc((size_t)G * NEU * 4);
    (void)ws_size; (void)n_in;

    int B = (N + 1023) / 1024;

    hipMemsetAsync(ncnt, 0, (size_t)N * 4, stream);

    // --- x -> bf16 copy ---
    tobf16_kernel<<<2048, 256, 0, stream>>>(x, xb, N * 32);

    // --- CSR build ---
    hist_kernel<<<2048, 256, 0, stream>>>(dst, ncnt, E);
    dinv_kernel<<<(N + 255) / 256, 256, 0, stream>>>(ncnt, dinv, N);
    scan_chunk_kernel<<<B, 256, 0, stream>>>(ncnt, rowptr + 1, bsum, N);
    scan_bsum_kernel<<<1, 256, 0, stream>>>(bsum, B);
    add_off_kernel<<<B, 256, 0, stream>>>(rowptr + 1, bsum, rowptr, cursor, N);
    build_csr_kernel<<<2048, 256, 0, stream>>>(src, dst, dinv, cursor, es2, E);

    // --- APPNP: 3 fused pull+combine steps (bf16 rows) ---
    pull_kernel<<<(N + 3) / 4, 256, 0, stream>>>(rowptr, es2, dinv, xb,  xb, hb0, N);
    pull_kernel<<<(N + 3) / 4, 256, 0, stream>>>(rowptr, es2, dinv, hb0, xb, hb1, N);
    pull_kernel<<<(N + 3) / 4, 256, 0, stream>>>(rowptr, es2, dinv, hb1, xb, hb0, N);

    // --- head ---
    fc1_kernel<<<(N + 31) / 32, 256, 0, stream>>>(hb0, nn1_w, nn1_b, h2, N);
    logits_kernel<<<(N + 255) / 256, 256, 0, stream>>>(cf, close_w, close_b, logits, N);
    boundary_kernel<<<2, 256, 0, stream>>>(batch, offs, N, G);
    softmax_kernel<<<G, 256, 0, stream>>>(logits, offs, p, G);
    pool_kernel<<<G, 256, 0, stream>>>(h2, p, offs, pooled, G);
    final_kernel<<<G, 64, 0, stream>>>(pooled, att1_w, att1_b, att2_w, att2_b, out, G);
}

// Round 6
// 434.389 us; speedup vs baseline: 10.1288x; 1.0827x over previous
//
#include <hip/hip_runtime.h>
#include <cstdint>
#include <cstddef>

// ---------------------------------------------------------------------------
// APPNPNet_Structural: APPNP (K=3) -> FC(128->64)+ReLU -> per-graph softmax
// pooling (weighted segment-max) -> MLP(64->16->1).
// Round 6: ALGEBRAIC REFACTOR — prop(x)@W1 == prop(x@W1), so FC1 runs first
// and propagation happens in 64-dim bf16 space (halves gather bytes again).
// Bias+ReLU fused into the last pull. CSR payload shrunk to 4B (src only).
// ---------------------------------------------------------------------------

#define DIN 128
#define NEU 64

// bf16 helpers: storage = ushort, math = f32.
__device__ inline float bf2f(unsigned short h) {
    return __uint_as_float(((unsigned)h) << 16);
}
__device__ inline unsigned short f2bf(float f) {   // round-to-nearest-even
    unsigned u = __float_as_uint(f);
    unsigned r = u + 0x7FFFu + ((u >> 16) & 1u);
    return (unsigned short)(r >> 16);
}

// ---------------- degree histogram (int) ----------------

__global__ void hist_kernel(const int* __restrict__ dst, int* __restrict__ cnt, int E) {
    int i = blockIdx.x * blockDim.x + threadIdx.x;
    int stride = gridDim.x * blockDim.x;
    for (; i < E; i += stride) atomicAdd(&cnt[dst[i]], 1);
}

__global__ void dinv_kernel(const int* __restrict__ cnt, float* __restrict__ dinv, int N) {
    int i = blockIdx.x * blockDim.x + threadIdx.x;
    if (i < N) dinv[i] = rsqrtf((float)cnt[i] + 1.0f);   // +1 = self loop
}

// ---------------- 3-kernel prefix scan of cnt[N] -> rowptr[N+1] ----------------

__global__ void scan_chunk_kernel(const int* __restrict__ cnt, int* __restrict__ rp1,
                                  int* __restrict__ bsum, int N) {
    __shared__ int sh[256];
    int t = threadIdx.x;
    int base = blockIdx.x * 1024 + t * 4;
    int a0 = (base + 0 < N) ? cnt[base + 0] : 0;
    int a1 = (base + 1 < N) ? cnt[base + 1] : 0;
    int a2 = (base + 2 < N) ? cnt[base + 2] : 0;
    int a3 = (base + 3 < N) ? cnt[base + 3] : 0;
    int s = a0 + a1 + a2 + a3;
    sh[t] = s; __syncthreads();
    for (int d = 1; d < 256; d <<= 1) {
        int v = (t >= d) ? sh[t - d] : 0;
        __syncthreads();
        sh[t] += v;
        __syncthreads();
    }
    int excl = sh[t] - s;
    if (base + 0 < N) rp1[base + 0] = excl + a0;
    if (base + 1 < N) rp1[base + 1] = excl + a0 + a1;
    if (base + 2 < N) rp1[base + 2] = excl + a0 + a1 + a2;
    if (base + 3 < N) rp1[base + 3] = excl + a0 + a1 + a2 + a3;
    if (t == 255) bsum[blockIdx.x] = sh[255];
}

__global__ void scan_bsum_kernel(int* __restrict__ bsum, int B) {
    __shared__ int sh[256];
    int t = threadIdx.x;
    int run = 0;
    for (int base = 0; base < B; base += 256) {
        int v = (base + t < B) ? bsum[base + t] : 0;
        __syncthreads();
        sh[t] = v; __syncthreads();
        for (int d = 1; d < 256; d <<= 1) {
            int u = (t >= d) ? sh[t - d] : 0;
            __syncthreads();
            sh[t] += u;
            __syncthreads();
        }
        if (base + t < B) bsum[base + t] = run + sh[t] - v;   // exclusive
        run += sh[255];
        __syncthreads();
    }
}

// rowptr finalize + cursor init
__global__ void add_off_kernel(int* __restrict__ rp1, const int* __restrict__ bsum,
                               int* __restrict__ rowptr0, int* __restrict__ cursor, int N) {
    int t = threadIdx.x;
    int base = blockIdx.x * 1024 + t * 4;
    int off = bsum[blockIdx.x];
#pragma unroll
    for (int j = 0; j < 4; j++) {
        int idx = base + j;
        if (idx < N) {
            int v = rp1[idx] + off;
            rp1[idx] = v;                 // rowptr[idx+1]
            if (idx + 1 < N) cursor[idx + 1] = v;
        }
    }
    if (blockIdx.x == 0 && t == 0) { rowptr0[0] = 0; cursor[0] = 0; }
}

// ---------------- bucket edges by dst (src only, 4B payload) ----------------

__global__ void build_csr_kernel(const int* __restrict__ src, const int* __restrict__ dst,
                                 int* __restrict__ cursor, int* __restrict__ es, int E) {
    int i = blockIdx.x * blockDim.x + threadIdx.x;
    int stride = gridDim.x * blockDim.x;
    for (; i < E; i += stride) {
        int pos = atomicAdd(&cursor[dst[i]], 1);
        es[pos] = src[i];
    }
}

// ---------------- FC1 (pre-propagation): y = x @ W1, bf16 out, no bias ----------------

__global__ __launch_bounds__(256) void fc1_kernel(
        const float* __restrict__ x, const float* __restrict__ W,
        ushort* __restrict__ yb, int N) {
    __shared__ float sW[DIN * NEU];   // 32 KB
    __shared__ float sx[32][DIN];     // 16 KB
    int tid = threadIdx.x;
    for (int k = tid; k < DIN * NEU; k += 256) sW[k] = W[k];
    int n0 = blockIdx.x * 32;
    for (int q = tid; q < 32 * 32; q += 256) {      // 32 rows x 32 float4
        int r = q >> 5, c4 = q & 31;
        int n = n0 + r;
        float4 v = (n < N) ? *((const float4*)(x + (size_t)n * DIN) + c4)
                           : make_float4(0.f, 0.f, 0.f, 0.f);
        *((float4*)&sx[r][0] + c4) = v;
    }
    __syncthreads();
    int j = tid & 63, wv = tid >> 6;
    int r0 = wv * 8;
    float acc[8];
#pragma unroll
    for (int r = 0; r < 8; r++) acc[r] = 0.f;
#pragma unroll 4
    for (int k = 0; k < DIN; k++) {
        float wk = sW[k * NEU + j];
#pragma unroll
        for (int r = 0; r < 8; r++) acc[r] = fmaf(sx[r0 + r][k], wk, acc[r]);
    }
#pragma unroll
    for (int r = 0; r < 8; r++) {
        int n = n0 + r0 + r;
        if (n < N) yb[(size_t)n * NEU + j] = f2bf(acc[r]);
    }
}

// ---------------- fused APPNP pull step, 64-dim bf16 rows ----------------
// one 64-lane wave per dst node. Edges in QUADS: 16 lanes per edge, each lane
// holds ushort4 (4 bf16) of the 64-dim row. f32 accum, shfl_xor(16|32)
// combine. FINAL step applies +b1, relu, writes f32 h2 for pooling.

template <bool FINAL>
__global__ __launch_bounds__(256) void pull_kernel(
        const int* __restrict__ rowptr, const int* __restrict__ es,
        const float* __restrict__ dinv, const ushort* __restrict__ hin,
        const ushort* __restrict__ yb, const float* __restrict__ b1,
        ushort* __restrict__ hout, float* __restrict__ h2out, int N) {
    int wid = threadIdx.x >> 6;
    int lane = threadIdx.x & 63;
    int quarter = lane >> 4;
    int l16 = lane & 15;
    int node = blockIdx.x * 4 + wid;
    if (node >= N) return;
    int beg = rowptr[node], end = rowptr[node + 1];
    float dd = dinv[node];
    float4 acc0 = make_float4(0.f, 0.f, 0.f, 0.f);
    float4 acc1 = make_float4(0.f, 0.f, 0.f, 0.f);
    int deg = end - beg;
    for (int base = 0; base < deg; base += 64) {
        int myi = base + lane;
        int msrc = (myi < deg) ? es[beg + myi] : 0;
        float mns = (myi < deg) ? dinv[msrc] * dd : 0.f;
        int cnt = min(64, deg - base);
        int quads = (cnt + 3) >> 2;
        int j = 0;
        for (; j + 1 < quads; j += 2) {
            int i0 = 4 * j + quarter;
            int i1 = 4 * j + 4 + quarter;
            int s0 = __shfl(msrc, i0);
            float n0 = __shfl(mns, i0);
            int s1 = __shfl(msrc, i1);
            float n1 = __shfl(mns, i1);
            ushort4 w0 = *((const ushort4*)(hin + (size_t)s0 * NEU) + l16);
            ushort4 w1 = *((const ushort4*)(hin + (size_t)s1 * NEU) + l16);
            acc0.x = fmaf(n0, bf2f(w0.x), acc0.x);
            acc0.y = fmaf(n0, bf2f(w0.y), acc0.y);
            acc0.z = fmaf(n0, bf2f(w0.z), acc0.z);
            acc0.w = fmaf(n0, bf2f(w0.w), acc0.w);
            acc1.x = fmaf(n1, bf2f(w1.x), acc1.x);
            acc1.y = fmaf(n1, bf2f(w1.y), acc1.y);
            acc1.z = fmaf(n1, bf2f(w1.z), acc1.z);
            acc1.w = fmaf(n1, bf2f(w1.w), acc1.w);
        }
        if (j < quads) {
            int i0 = 4 * j + quarter;
            int s0 = __shfl(msrc, i0);
            float n0 = __shfl(mns, i0);
            ushort4 w0 = *((const ushort4*)(hin + (size_t)s0 * NEU) + l16);
            acc0.x = fmaf(n0, bf2f(w0.x), acc0.x);
            acc0.y = fmaf(n0, bf2f(w0.y), acc0.y);
            acc0.z = fmaf(n0, bf2f(w0.z), acc0.z);
            acc0.w = fmaf(n0, bf2f(w0.w), acc0.w);
        }
    }
    float4 acc;
    acc.x = acc0.x + acc1.x;
    acc.y = acc0.y + acc1.y;
    acc.z = acc0.z + acc1.z;
    acc.w = acc0.w + acc1.w;
    acc.x += __shfl_xor(acc.x, 16);
    acc.y += __shfl_xor(acc.y, 16);
    acc.z += __shfl_xor(acc.z, 16);
    acc.w += __shfl_xor(acc.w, 16);
    acc.x += __shfl_xor(acc.x, 32);
    acc.y += __shfl_xor(acc.y, 32);
    acc.z += __shfl_xor(acc.z, 32);
    acc.w += __shfl_xor(acc.w, 32);
    if (quarter == 0) {
        ushort4 hv = *((const ushort4*)(hin + (size_t)node * NEU) + l16);
        ushort4 xv = *((const ushort4*)(yb + (size_t)node * NEU) + l16);
        float d2 = dd * dd;
        float vx = 0.9f * (acc.x + d2 * bf2f(hv.x)) + 0.1f * bf2f(xv.x);
        float vy = 0.9f * (acc.y + d2 * bf2f(hv.y)) + 0.1f * bf2f(xv.y);
        float vz = 0.9f * (acc.z + d2 * bf2f(hv.z)) + 0.1f * bf2f(xv.z);
        float vw = 0.9f * (acc.w + d2 * bf2f(hv.w)) + 0.1f * bf2f(xv.w);
        if (FINAL) {
            float4 bb = *((const float4*)b1 + l16);
            float4 o;
            o.x = fmaxf(vx + bb.x, 0.f);
            o.y = fmaxf(vy + bb.y, 0.f);
            o.z = fmaxf(vz + bb.z, 0.f);
            o.w = fmaxf(vw + bb.w, 0.f);
            *((float4*)(h2out + (size_t)node * NEU) + l16) = o;
        } else {
            ushort4 o;
            o.x = f2bf(vx); o.y = f2bf(vy); o.z = f2bf(vz); o.w = f2bf(vw);
            *((ushort4*)(hout + (size_t)node * NEU) + l16) = o;
        }
    }
}

// ---------------- closeness logits ----------------

__global__ void logits_kernel(const float* __restrict__ cf, const float* __restrict__ cw,
                              const float* __restrict__ cb, float* __restrict__ logits, int N) {
    int i = blockIdx.x * blockDim.x + threadIdx.x;
    if (i >= N) return;
    const float4* c = (const float4*)(cf + (size_t)i * 8);
    float4 a = c[0], b = c[1];
    float s = a.x * cw[0] + a.y * cw[1] + a.z * cw[2] + a.w * cw[3]
            + b.x * cw[4] + b.y * cw[5] + b.z * cw[6] + b.w * cw[7] + cb[0];
    logits[i] = s;
}

// ---------------- per-graph offsets via binary search (batch sorted) ----------------

__global__ void boundary_kernel(const int* __restrict__ batch, int* __restrict__ offs,
                                int N, int G) {
    int g = blockIdx.x * blockDim.x + threadIdx.x;   // 0..G inclusive
    if (g > G) return;
    int lo = 0, hi = N;
    while (lo < hi) {
        int mid = (lo + hi) >> 1;
        if (batch[mid] < g) lo = mid + 1; else hi = mid;
    }
    offs[g] = lo;
}

// ---------------- segment softmax -> p (scaled by count) ----------------

__global__ __launch_bounds__(256) void softmax_kernel(
        const float* __restrict__ logits, const int* __restrict__ offs,
        float* __restrict__ p, int G) {
    int g = blockIdx.x;
    int s0 = offs[g], e0 = offs[g + 1];
    int tid = threadIdx.x;
    __shared__ float red[256];
    float m = -INFINITY;
    for (int i = s0 + tid; i < e0; i += 256) m = fmaxf(m, logits[i]);
    red[tid] = m; __syncthreads();
    for (int w = 128; w > 0; w >>= 1) {
        if (tid < w) red[tid] = fmaxf(red[tid], red[tid + w]);
        __syncthreads();
    }
    m = red[0]; __syncthreads();
    float z = 0.f;
    for (int i = s0 + tid; i < e0; i += 256) z += expf(logits[i] - m);
    red[tid] = z; __syncthreads();
    for (int w = 128; w > 0; w >>= 1) {
        if (tid < w) red[tid] += red[tid + w];
        __syncthreads();
    }
    z = red[0];
    float scale = (float)(e0 - s0) / z;
    for (int i = s0 + tid; i < e0; i += 256) p[i] = expf(logits[i] - m) * scale;
}

// ---------------- weighted segment max-pool ----------------

__global__ __launch_bounds__(256) void pool_kernel(
        const float* __restrict__ h2, const float* __restrict__ p,
        const int* __restrict__ offs, float* __restrict__ pooled, int G) {
    int g = blockIdx.x;
    int s0 = offs[g], e0 = offs[g + 1];
    int tid = threadIdx.x;
    int j = tid & 63, r = tid >> 6;
    float mx = -INFINITY;
    for (int i = s0 + r; i < e0; i += 4)
        mx = fmaxf(mx, p[i] * h2[(size_t)i * NEU + j]);
    __shared__ float red[256];
    red[tid] = mx;
    __syncthreads();
    if (r == 0) {
        float m0 = fmaxf(fmaxf(red[j], red[64 + j]), fmaxf(red[128 + j], red[192 + j]));
        pooled[(size_t)g * NEU + j] = m0;
    }
}

// ---------------- final MLP 64->16->1 ----------------

__global__ void final_kernel(const float* __restrict__ pooled, const float* __restrict__ w1,
                             const float* __restrict__ b1, const float* __restrict__ w2,
                             const float* __restrict__ b2, float* __restrict__ out, int G) {
    int g = blockIdx.x;
    int tid = threadIdx.x;   // 64 threads
    __shared__ float sp[64];
    __shared__ float sa[16];
    sp[tid] = pooled[(size_t)g * 64 + tid];
    __syncthreads();
    if (tid < 16) {
        float acc = b1[tid];
#pragma unroll
        for (int k = 0; k < 64; k++) acc = fmaf(sp[k], w1[k * 16 + tid], acc);
        sa[tid] = fmaxf(acc, 0.f);
    }
    __syncthreads();
    if (tid == 0) {
        float o = b2[0];
#pragma unroll
        for (int k = 0; k < 16; k++) o = fmaf(sa[k], w2[k], o);
        out[g] = o;
    }
}

// ---------------------------------------------------------------------------

extern "C" void kernel_launch(void* const* d_in, const int* in_sizes, int n_in,
                              void* d_out, int out_size, void* d_ws, size_t ws_size,
                              hipStream_t stream) {
    const float* x       = (const float*)d_in[0];
    const float* cf      = (const float*)d_in[1];
    const int*   ei      = (const int*)d_in[2];
    const int*   batch   = (const int*)d_in[3];
    const float* nn1_w   = (const float*)d_in[5];
    const float* nn1_b   = (const float*)d_in[6];
    const float* close_w = (const float*)d_in[7];
    const float* close_b = (const float*)d_in[8];
    const float* att1_w  = (const float*)d_in[9];
    const float* att1_b  = (const float*)d_in[10];
    const float* att2_w  = (const float*)d_in[11];
    const float* att2_b  = (const float*)d_in[12];
    float* out = (float*)d_out;

    int N = in_sizes[0] / DIN;
    int E = in_sizes[2] / 2;
    int G = out_size;

    const int* src = ei;
    const int* dst = ei + E;

    char* w = (char*)d_ws;
    size_t off = 0;
    auto alloc = [&](size_t bytes) -> void* {
        void* ptr = w + off;
        off += (bytes + 511) & ~(size_t)511;
        return ptr;
    };
    ushort* yb     = (ushort*)alloc((size_t)N * NEU * 2);   // x @ W1, bf16
    ushort* hb0    = (ushort*)alloc((size_t)N * NEU * 2);
    ushort* hb1    = (ushort*)alloc((size_t)N * NEU * 2);
    float* h2      = (float*)alloc((size_t)N * NEU * 4);    // relu(prop+b1), f32
    float* dinv    = (float*)alloc((size_t)N * 4);
    int*   ncnt    = (int*)alloc((size_t)N * 4);
    int*   rowptr  = (int*)alloc(((size_t)N + 1) * 4);
    int*   cursor  = (int*)alloc((size_t)N * 4);
    int*   bsum    = (int*)alloc(512 * 4);
    int*   es      = (int*)alloc((size_t)E * 4);
    float* logits  = (float*)alloc((size_t)N * 4);
    float* p       = (float*)alloc((size_t)N * 4);
    int*   offs    = (int*)alloc(((size_t)G + 1) * 4);
    float* pooled  = (float*)alloc((size_t)G * NEU * 4);
    (void)ws_size; (void)n_in;

    int B = (N + 1023) / 1024;

    hipMemsetAsync(ncnt, 0, (size_t)N * 4, stream);

    // --- y = x @ W1 (propagation commutes with right-mul) ---
    fc1_kernel<<<(N + 31) / 32, 256, 0, stream>>>(x, nn1_w, yb, N);

    // --- CSR build ---
    hist_kernel<<<2048, 256, 0, stream>>>(dst, ncnt, E);
    dinv_kernel<<<(N + 255) / 256, 256, 0, stream>>>(ncnt, dinv, N);
    scan_chunk_kernel<<<B, 256, 0, stream>>>(ncnt, rowptr + 1, bsum, N);
    scan_bsum_kernel<<<1, 256, 0, stream>>>(bsum, B);
    add_off_kernel<<<B, 256, 0, stream>>>(rowptr + 1, bsum, rowptr, cursor, N);
    build_csr_kernel<<<2048, 256, 0, stream>>>(src, dst, cursor, es, E);

    // --- APPNP: 3 fused pull steps in 64-dim bf16; last applies b1+relu ---
    pull_kernel<false><<<(N + 3) / 4, 256, 0, stream>>>(rowptr, es, dinv, yb,  yb, nn1_b, hb0, nullptr, N);
    pull_kernel<false><<<(N + 3) / 4, 256, 0, stream>>>(rowptr, es, dinv, hb0, yb, nn1_b, hb1, nullptr, N);
    pull_kernel<true ><<<(N + 3) / 4, 256, 0, stream>>>(rowptr, es, dinv, hb1, yb, nn1_b, nullptr, h2, N);

    // --- head ---
    logits_kernel<<<(N + 255) / 256, 256, 0, stream>>>(cf, close_w, close_b, logits, N);
    boundary_kernel<<<2, 256, 0, stream>>>(batch, offs, N, G);
    softmax_kernel<<<G, 256, 0, stream>>>(logits, offs, p, G);
    pool_kernel<<<G, 256, 0, stream>>>(h2, p, offs, pooled, G);
    final_kernel<<<G, 64, 0, stream>>>(pooled, att1_w, att1_b, att2_w, att2_b, out, G);
}

// Round 7
// 401.809 us; speedup vs baseline: 10.9501x; 1.0811x over previous
//
#include <hip/hip_runtime.h>
#include <cstdint>
#include <cstddef>

// ---------------------------------------------------------------------------
// APPNPNet_Structural: FC1-first (prop commutes with right-mul) -> APPNP K=3
// in 64-dim bf16 -> segment softmax pooling -> MLP(64->16->1).
// Round 7: two-phase binned CSR build. Old single-kernel scatter wrote ~107MB
// (line-granular amplification over a 6.4MB range). Phase A bins edges into
// 98 coarse buckets (LDS histogram + range reservation, contiguous appends);
// Phase B scatters within L2-resident 64KB regions.
// ---------------------------------------------------------------------------

#define DIN 128
#define NEU 64
#define BKSHIFT 10          // bucket = dst >> 10  (1024 nodes per bucket)
#define BKCAP 32768         // per-bucket capacity (mean ~16.4K, >100 sigma slack)
#define MAXNB 128

// bf16 helpers: storage = ushort, math = f32.
__device__ inline float bf2f(unsigned short h) {
    return __uint_as_float(((unsigned)h) << 16);
}
__device__ inline unsigned short f2bf(float f) {   // round-to-nearest-even
    unsigned u = __float_as_uint(f);
    unsigned r = u + 0x7FFFu + ((u >> 16) & 1u);
    return (unsigned short)(r >> 16);
}

// ---------------- degree histogram (int) ----------------

__global__ void hist_kernel(const int* __restrict__ dst, int* __restrict__ cnt, int E) {
    int i = blockIdx.x * blockDim.x + threadIdx.x;
    int stride = gridDim.x * blockDim.x;
    for (; i < E; i += stride) atomicAdd(&cnt[dst[i]], 1);
}

__global__ void dinv_kernel(const int* __restrict__ cnt, float* __restrict__ dinv, int N) {
    int i = blockIdx.x * blockDim.x + threadIdx.x;
    if (i < N) dinv[i] = rsqrtf((float)cnt[i] + 1.0f);   // +1 = self loop
}

// ---------------- 3-kernel prefix scan of cnt[N] -> rowptr[N+1] ----------------

__global__ void scan_chunk_kernel(const int* __restrict__ cnt, int* __restrict__ rp1,
                                  int* __restrict__ bsum, int N) {
    __shared__ int sh[256];
    int t = threadIdx.x;
    int base = blockIdx.x * 1024 + t * 4;
    int a0 = (base + 0 < N) ? cnt[base + 0] : 0;
    int a1 = (base + 1 < N) ? cnt[base + 1] : 0;
    int a2 = (base + 2 < N) ? cnt[base + 2] : 0;
    int a3 = (base + 3 < N) ? cnt[base + 3] : 0;
    int s = a0 + a1 + a2 + a3;
    sh[t] = s; __syncthreads();
    for (int d = 1; d < 256; d <<= 1) {
        int v = (t >= d) ? sh[t - d] : 0;
        __syncthreads();
        sh[t] += v;
        __syncthreads();
    }
    int excl = sh[t] - s;
    if (base + 0 < N) rp1[base + 0] = excl + a0;
    if (base + 1 < N) rp1[base + 1] = excl + a0 + a1;
    if (base + 2 < N) rp1[base + 2] = excl + a0 + a1 + a2;
    if (base + 3 < N) rp1[base + 3] = excl + a0 + a1 + a2 + a3;
    if (t == 255) bsum[blockIdx.x] = sh[255];
}

__global__ void scan_bsum_kernel(int* __restrict__ bsum, int B) {
    __shared__ int sh[256];
    int t = threadIdx.x;
    int run = 0;
    for (int base = 0; base < B; base += 256) {
        int v = (base + t < B) ? bsum[base + t] : 0;
        __syncthreads();
        sh[t] = v; __syncthreads();
        for (int d = 1; d < 256; d <<= 1) {
            int u = (t >= d) ? sh[t - d] : 0;
            __syncthreads();
            sh[t] += u;
            __syncthreads();
        }
        if (base + t < B) bsum[base + t] = run + sh[t] - v;   // exclusive
        run += sh[255];
        __syncthreads();
    }
}

// rowptr finalize + cursor init
__global__ void add_off_kernel(int* __restrict__ rp1, const int* __restrict__ bsum,
                               int* __restrict__ rowptr0, int* __restrict__ cursor, int N) {
    int t = threadIdx.x;
    int base = blockIdx.x * 1024 + t * 4;
    int off = bsum[blockIdx.x];
#pragma unroll
    for (int j = 0; j < 4; j++) {
        int idx = base + j;
        if (idx < N) {
            int v = rp1[idx] + off;
            rp1[idx] = v;                 // rowptr[idx+1]
            if (idx + 1 < N) cursor[idx + 1] = v;
        }
    }
    if (blockIdx.x == 0 && t == 0) { rowptr0[0] = 0; cursor[0] = 0; }
}

// ---------------- Phase A: coarse binning with block-local aggregation ----------------

__global__ __launch_bounds__(256) void binA_kernel(
        const int* __restrict__ src, const int* __restrict__ dst,
        int* __restrict__ bcur, int2* __restrict__ pairs, int E, int NB) {
    __shared__ int hist[MAXNB];
    __shared__ int cur[MAXNB];
    int nchunk = gridDim.x;
    int chunk = (E + nchunk - 1) / nchunk;
    int lo = blockIdx.x * chunk;
    int hi = min(E, lo + chunk);
    int t = threadIdx.x;
    for (int b = t; b < NB; b += 256) hist[b] = 0;
    __syncthreads();
    for (int i = lo + t; i < hi; i += 256)
        atomicAdd(&hist[dst[i] >> BKSHIFT], 1);
    __syncthreads();
    for (int b = t; b < NB; b += 256)
        cur[b] = atomicAdd(&bcur[b], hist[b]);
    __syncthreads();
    for (int i = lo + t; i < hi; i += 256) {
        int d = dst[i];
        int b = d >> BKSHIFT;
        int pos = atomicAdd(&cur[b], 1);
        pairs[(size_t)b * BKCAP + pos] = make_int2(src[i], d);
    }
}

// ---------------- Phase B: scatter within L2-resident bucket regions ----------------

__global__ __launch_bounds__(256) void binB_kernel(
        const int* __restrict__ bcnt, const int2* __restrict__ pairs,
        int* __restrict__ cursor, int* __restrict__ es, int NB) {
    int bucket = blockIdx.x >> 2;       // 4 blocks per bucket
    int part = blockIdx.x & 3;
    if (bucket >= NB) return;
    int n = bcnt[bucket];
    const int2* pb = pairs + (size_t)bucket * BKCAP;
    for (int i = part * 256 + threadIdx.x; i < n; i += 1024) {
        int2 e = pb[i];
        int pos = atomicAdd(&cursor[e.y], 1);
        es[pos] = e.x;
    }
}

// ---------------- FC1 (pre-propagation): y = x @ W1, bf16 out, no bias ----------------

__global__ __launch_bounds__(256) void fc1_kernel(
        const float* __restrict__ x, const float* __restrict__ W,
        ushort* __restrict__ yb, int N) {
    __shared__ float sW[DIN * NEU];   // 32 KB
    __shared__ float sx[32][DIN];     // 16 KB
    int tid = threadIdx.x;
    for (int k = tid; k < DIN * NEU; k += 256) sW[k] = W[k];
    int n0 = blockIdx.x * 32;
    for (int q = tid; q < 32 * 32; q += 256) {      // 32 rows x 32 float4
        int r = q >> 5, c4 = q & 31;
        int n = n0 + r;
        float4 v = (n < N) ? *((const float4*)(x + (size_t)n * DIN) + c4)
                           : make_float4(0.f, 0.f, 0.f, 0.f);
        *((float4*)&sx[r][0] + c4) = v;
    }
    __syncthreads();
    int j = tid & 63, wv = tid >> 6;
    int r0 = wv * 8;
    float acc[8];
#pragma unroll
    for (int r = 0; r < 8; r++) acc[r] = 0.f;
#pragma unroll 4
    for (int k = 0; k < DIN; k++) {
        float wk = sW[k * NEU + j];
#pragma unroll
        for (int r = 0; r < 8; r++) acc[r] = fmaf(sx[r0 + r][k], wk, acc[r]);
    }
#pragma unroll
    for (int r = 0; r < 8; r++) {
        int n = n0 + r0 + r;
        if (n < N) yb[(size_t)n * NEU + j] = f2bf(acc[r]);
    }
}

// ---------------- fused APPNP pull step, 64-dim bf16 rows ----------------

template <bool FINAL>
__global__ __launch_bounds__(256) void pull_kernel(
        const int* __restrict__ rowptr, const int* __restrict__ es,
        const float* __restrict__ dinv, const ushort* __restrict__ hin,
        const ushort* __restrict__ yb, const float* __restrict__ b1,
        ushort* __restrict__ hout, float* __restrict__ h2out, int N) {
    int wid = threadIdx.x >> 6;
    int lane = threadIdx.x & 63;
    int quarter = lane >> 4;
    int l16 = lane & 15;
    int node = blockIdx.x * 4 + wid;
    if (node >= N) return;
    int beg = rowptr[node], end = rowptr[node + 1];
    float dd = dinv[node];
    float4 acc0 = make_float4(0.f, 0.f, 0.f, 0.f);
    float4 acc1 = make_float4(0.f, 0.f, 0.f, 0.f);
    int deg = end - beg;
    for (int base = 0; base < deg; base += 64) {
        int myi = base + lane;
        int msrc = (myi < deg) ? es[beg + myi] : 0;
        float mns = (myi < deg) ? dinv[msrc] * dd : 0.f;
        int cnt = min(64, deg - base);
        int quads = (cnt + 3) >> 2;
        int j = 0;
        for (; j + 1 < quads; j += 2) {
            int i0 = 4 * j + quarter;
            int i1 = 4 * j + 4 + quarter;
            int s0 = __shfl(msrc, i0);
            float n0 = __shfl(mns, i0);
            int s1 = __shfl(msrc, i1);
            float n1 = __shfl(mns, i1);
            ushort4 w0 = *((const ushort4*)(hin + (size_t)s0 * NEU) + l16);
            ushort4 w1 = *((const ushort4*)(hin + (size_t)s1 * NEU) + l16);
            acc0.x = fmaf(n0, bf2f(w0.x), acc0.x);
            acc0.y = fmaf(n0, bf2f(w0.y), acc0.y);
            acc0.z = fmaf(n0, bf2f(w0.z), acc0.z);
            acc0.w = fmaf(n0, bf2f(w0.w), acc0.w);
            acc1.x = fmaf(n1, bf2f(w1.x), acc1.x);
            acc1.y = fmaf(n1, bf2f(w1.y), acc1.y);
            acc1.z = fmaf(n1, bf2f(w1.z), acc1.z);
            acc1.w = fmaf(n1, bf2f(w1.w), acc1.w);
        }
        if (j < quads) {
            int i0 = 4 * j + quarter;
            int s0 = __shfl(msrc, i0);
            float n0 = __shfl(mns, i0);
            ushort4 w0 = *((const ushort4*)(hin + (size_t)s0 * NEU) + l16);
            acc0.x = fmaf(n0, bf2f(w0.x), acc0.x);
            acc0.y = fmaf(n0, bf2f(w0.y), acc0.y);
            acc0.z = fmaf(n0, bf2f(w0.z), acc0.z);
            acc0.w = fmaf(n0, bf2f(w0.w), acc0.w);
        }
    }
    float4 acc;
    acc.x = acc0.x + acc1.x;
    acc.y = acc0.y + acc1.y;
    acc.z = acc0.z + acc1.z;
    acc.w = acc0.w + acc1.w;
    acc.x += __shfl_xor(acc.x, 16);
    acc.y += __shfl_xor(acc.y, 16);
    acc.z += __shfl_xor(acc.z, 16);
    acc.w += __shfl_xor(acc.w, 16);
    acc.x += __shfl_xor(acc.x, 32);
    acc.y += __shfl_xor(acc.y, 32);
    acc.z += __shfl_xor(acc.z, 32);
    acc.w += __shfl_xor(acc.w, 32);
    if (quarter == 0) {
        ushort4 hv = *((const ushort4*)(hin + (size_t)node * NEU) + l16);
        ushort4 xv = *((const ushort4*)(yb + (size_t)node * NEU) + l16);
        float d2 = dd * dd;
        float vx = 0.9f * (acc.x + d2 * bf2f(hv.x)) + 0.1f * bf2f(xv.x);
        float vy = 0.9f * (acc.y + d2 * bf2f(hv.y)) + 0.1f * bf2f(xv.y);
        float vz = 0.9f * (acc.z + d2 * bf2f(hv.z)) + 0.1f * bf2f(xv.z);
        float vw = 0.9f * (acc.w + d2 * bf2f(hv.w)) + 0.1f * bf2f(xv.w);
        if (FINAL) {
            float4 bb = *((const float4*)b1 + l16);
            float4 o;
            o.x = fmaxf(vx + bb.x, 0.f);
            o.y = fmaxf(vy + bb.y, 0.f);
            o.z = fmaxf(vz + bb.z, 0.f);
            o.w = fmaxf(vw + bb.w, 0.f);
            *((float4*)(h2out + (size_t)node * NEU) + l16) = o;
        } else {
            ushort4 o;
            o.x = f2bf(vx); o.y = f2bf(vy); o.z = f2bf(vz); o.w = f2bf(vw);
            *((ushort4*)(hout + (size_t)node * NEU) + l16) = o;
        }
    }
}

// ---------------- closeness logits ----------------

__global__ void logits_kernel(const float* __restrict__ cf, const float* __restrict__ cw,
                              const float* __restrict__ cb, float* __restrict__ logits, int N) {
    int i = blockIdx.x * blockDim.x + threadIdx.x;
    if (i >= N) return;
    const float4* c = (const float4*)(cf + (size_t)i * 8);
    float4 a = c[0], b = c[1];
    float s = a.x * cw[0] + a.y * cw[1] + a.z * cw[2] + a.w * cw[3]
            + b.x * cw[4] + b.y * cw[5] + b.z * cw[6] + b.w * cw[7] + cb[0];
    logits[i] = s;
}

// ---------------- per-graph offsets via binary search (batch sorted) ----------------

__global__ void boundary_kernel(const int* __restrict__ batch, int* __restrict__ offs,
                                int N, int G) {
    int g = blockIdx.x * blockDim.x + threadIdx.x;   // 0..G inclusive
    if (g > G) return;
    int lo = 0, hi = N;
    while (lo < hi) {
        int mid = (lo + hi) >> 1;
        if (batch[mid] < g) lo = mid + 1; else hi = mid;
    }
    offs[g] = lo;
}

// ---------------- segment softmax -> p (scaled by count) ----------------

__global__ __launch_bounds__(256) void softmax_kernel(
        const float* __restrict__ logits, const int* __restrict__ offs,
        float* __restrict__ p, int G) {
    int g = blockIdx.x;
    int s0 = offs[g], e0 = offs[g + 1];
    int tid = threadIdx.x;
    __shared__ float red[256];
    float m = -INFINITY;
    for (int i = s0 + tid; i < e0; i += 256) m = fmaxf(m, logits[i]);
    red[tid] = m; __syncthreads();
    for (int w = 128; w > 0; w >>= 1) {
        if (tid < w) red[tid] = fmaxf(red[tid], red[tid + w]);
        __syncthreads();
    }
    m = red[0]; __syncthreads();
    float z = 0.f;
    for (int i = s0 + tid; i < e0; i += 256) z += expf(logits[i] - m);
    red[tid] = z; __syncthreads();
    for (int w = 128; w > 0; w >>= 1) {
        if (tid < w) red[tid] += red[tid + w];
        __syncthreads();
    }
    z = red[0];
    float scale = (float)(e0 - s0) / z;
    for (int i = s0 + tid; i < e0; i += 256) p[i] = expf(logits[i] - m) * scale;
}

// ---------------- weighted segment max-pool ----------------

__global__ __launch_bounds__(256) void pool_kernel(
        const float* __restrict__ h2, const float* __restrict__ p,
        const int* __restrict__ offs, float* __restrict__ pooled, int G) {
    int g = blockIdx.x;
    int s0 = offs[g], e0 = offs[g + 1];
    int tid = threadIdx.x;
    int j = tid & 63, r = tid >> 6;
    float mx = -INFINITY;
    for (int i = s0 + r; i < e0; i += 4)
        mx = fmaxf(mx, p[i] * h2[(size_t)i * NEU + j]);
    __shared__ float red[256];
    red[tid] = mx;
    __syncthreads();
    if (r == 0) {
        float m0 = fmaxf(fmaxf(red[j], red[64 + j]), fmaxf(red[128 + j], red[192 + j]));
        pooled[(size_t)g * NEU + j] = m0;
    }
}

// ---------------- final MLP 64->16->1 ----------------

__global__ void final_kernel(const float* __restrict__ pooled, const float* __restrict__ w1,
                             const float* __restrict__ b1, const float* __restrict__ w2,
                             const float* __restrict__ b2, float* __restrict__ out, int G) {
    int g = blockIdx.x;
    int tid = threadIdx.x;   // 64 threads
    __shared__ float sp[64];
    __shared__ float sa[16];
    sp[tid] = pooled[(size_t)g * 64 + tid];
    __syncthreads();
    if (tid < 16) {
        float acc = b1[tid];
#pragma unroll
        for (int k = 0; k < 64; k++) acc = fmaf(sp[k], w1[k * 16 + tid], acc);
        sa[tid] = fmaxf(acc, 0.f);
    }
    __syncthreads();
    if (tid == 0) {
        float o = b2[0];
#pragma unroll
        for (int k = 0; k < 16; k++) o = fmaf(sa[k], w2[k], o);
        out[g] = o;
    }
}

// ---------------------------------------------------------------------------

extern "C" void kernel_launch(void* const* d_in, const int* in_sizes, int n_in,
                              void* d_out, int out_size, void* d_ws, size_t ws_size,
                              hipStream_t stream) {
    const float* x       = (const float*)d_in[0];
    const float* cf      = (const float*)d_in[1];
    const int*   ei      = (const int*)d_in[2];
    const int*   batch   = (const int*)d_in[3];
    const float* nn1_w   = (const float*)d_in[5];
    const float* nn1_b   = (const float*)d_in[6];
    const float* close_w = (const float*)d_in[7];
    const float* close_b = (const float*)d_in[8];
    const float* att1_w  = (const float*)d_in[9];
    const float* att1_b  = (const float*)d_in[10];
    const float* att2_w  = (const float*)d_in[11];
    const float* att2_b  = (const float*)d_in[12];
    float* out = (float*)d_out;

    int N = in_sizes[0] / DIN;
    int E = in_sizes[2] / 2;
    int G = out_size;

    const int* src = ei;
    const int* dst = ei + E;

    char* w = (char*)d_ws;
    size_t off = 0;
    auto alloc = [&](size_t bytes) -> void* {
        void* ptr = w + off;
        off += (bytes + 511) & ~(size_t)511;
        return ptr;
    };
    int NB = (N + (1 << BKSHIFT) - 1) >> BKSHIFT;   // 98 for N=100K (<= MAXNB)

    ushort* yb     = (ushort*)alloc((size_t)N * NEU * 2);   // x @ W1, bf16
    ushort* hb0    = (ushort*)alloc((size_t)N * NEU * 2);
    ushort* hb1    = (ushort*)alloc((size_t)N * NEU * 2);
    float* h2      = (float*)alloc((size_t)N * NEU * 4);    // relu(prop+b1), f32
    float* dinv    = (float*)alloc((size_t)N * 4);
    int*   ncnt    = (int*)alloc((size_t)N * 4);
    int*   rowptr  = (int*)alloc(((size_t)N + 1) * 4);
    int*   cursor  = (int*)alloc((size_t)N * 4);
    int*   bsum    = (int*)alloc(512 * 4);
    int*   es      = (int*)alloc((size_t)E * 4);
    int*   bcur    = (int*)alloc((size_t)NB * 4);
    int2*  pairs   = (int2*)alloc((size_t)NB * BKCAP * 8);
    float* logits  = (float*)alloc((size_t)N * 4);
    float* p       = (float*)alloc((size_t)N * 4);
    int*   offs    = (int*)alloc(((size_t)G + 1) * 4);
    float* pooled  = (float*)alloc((size_t)G * NEU * 4);
    (void)ws_size; (void)n_in;

    int B = (N + 1023) / 1024;

    hipMemsetAsync(ncnt, 0, (size_t)N * 4, stream);
    hipMemsetAsync(bcur, 0, (size_t)NB * 4, stream);

    // --- y = x @ W1 (propagation commutes with right-mul) ---
    fc1_kernel<<<(N + 31) / 32, 256, 0, stream>>>(x, nn1_w, yb, N);

    // --- CSR build: hist/scan + two-phase binned scatter ---
    hist_kernel<<<2048, 256, 0, stream>>>(dst, ncnt, E);
    binA_kernel<<<256, 256, 0, stream>>>(src, dst, bcur, pairs, E, NB);
    dinv_kernel<<<(N + 255) / 256, 256, 0, stream>>>(ncnt, dinv, N);
    scan_chunk_kernel<<<B, 256, 0, stream>>>(ncnt, rowptr + 1, bsum, N);
    scan_bsum_kernel<<<1, 256, 0, stream>>>(bsum, B);
    add_off_kernel<<<B, 256, 0, stream>>>(rowptr + 1, bsum, rowptr, cursor, N);
    binB_kernel<<<NB * 4, 256, 0, stream>>>(bcur, pairs, cursor, es, NB);

    // --- APPNP: 3 fused pull steps in 64-dim bf16; last applies b1+relu ---
    pull_kernel<false><<<(N + 3) / 4, 256, 0, stream>>>(rowptr, es, dinv, yb,  yb, nn1_b, hb0, nullptr, N);
    pull_kernel<false><<<(N + 3) / 4, 256, 0, stream>>>(rowptr, es, dinv, hb0, yb, nn1_b, hb1, nullptr, N);
    pull_kernel<true ><<<(N + 3) / 4, 256, 0, stream>>>(rowptr, es, dinv, hb1, yb, nn1_b, nullptr, h2, N);

    // --- head ---
    logits_kernel<<<(N + 255) / 256, 256, 0, stream>>>(cf, close_w, close_b, logits, N);
    boundary_kernel<<<2, 256, 0, stream>>>(batch, offs, N, G);
    softmax_kernel<<<G, 256, 0, stream>>>(logits, offs, p, G);
    pool_kernel<<<G, 256, 0, stream>>>(h2, p, offs, pooled, G);
    final_kernel<<<G, 64, 0, stream>>>(pooled, att1_w, att1_b, att2_w, att2_b, out, G);
}

// Round 8
// 274.430 us; speedup vs baseline: 16.0327x; 1.4642x over previous
//
#include <hip/hip_runtime.h>
#include <cstdint>
#include <cstddef>

// ---------------------------------------------------------------------------
// APPNPNet_Structural: FC1-first (prop commutes with right-mul) -> APPNP K=3
// in 64-dim bf16 -> segment softmax pooling -> MLP(64->16->1).
// Round 8: CSR build via per-bucket LDS counting sort. binA packs
// (src<<9 | local_dst) into 4B and bins into 196 buckets of 512 nodes.
// binB (one block/bucket): LDS histogram -> LDS scan (= rowptr + dinv,
// replacing 5 global kernels) -> LDS scatter -> contiguous stream-out.
// Kills the line-granular write amplification (100MB -> ~7MB).
// ---------------------------------------------------------------------------

#define DIN 128
#define NEU 64
#define BK2 512            // nodes per bucket
#define BKSHIFT2 9
#define BKCAP 16384        // per-bucket global staging capacity (mean 8192)
#define ESCAP 12288        // per-bucket LDS sort capacity (48KB, mean+45sigma)
#define MAXNB 256

// bf16 helpers: storage = ushort, math = f32.
__device__ inline float bf2f(unsigned short h) {
    return __uint_as_float(((unsigned)h) << 16);
}
__device__ inline unsigned short f2bf(float f) {   // round-to-nearest-even
    unsigned u = __float_as_uint(f);
    unsigned r = u + 0x7FFFu + ((u >> 16) & 1u);
    return (unsigned short)(r >> 16);
}

// ---------------- Phase A: coarse binning, packed 4B payload ----------------

__global__ __launch_bounds__(256) void binA_kernel(
        const int* __restrict__ src, const int* __restrict__ dst,
        int* __restrict__ bcur, int* __restrict__ pk, int E, int NB) {
    __shared__ int hist[MAXNB];
    __shared__ int cur[MAXNB];
    int nchunk = gridDim.x;
    int chunk = (E + nchunk - 1) / nchunk;
    int lo = blockIdx.x * chunk;
    int hi = min(E, lo + chunk);
    int t = threadIdx.x;
    for (int b = t; b < NB; b += 256) hist[b] = 0;
    __syncthreads();
    for (int i = lo + t; i < hi; i += 256)
        atomicAdd(&hist[dst[i] >> BKSHIFT2], 1);
    __syncthreads();
    for (int b = t; b < NB; b += 256)
        cur[b] = atomicAdd(&bcur[b], hist[b]);
    __syncthreads();
    for (int i = lo + t; i < hi; i += 256) {
        int d = dst[i];
        int b = d >> BKSHIFT2;
        int pos = atomicAdd(&cur[b], 1);
        pk[(size_t)b * BKCAP + pos] = (src[i] << BKSHIFT2) | (d & (BK2 - 1));
    }
}

// ---------------- exclusive scan of bucket counts ----------------

__global__ void bscan_kernel(const int* __restrict__ bcur, int* __restrict__ bbase, int NB) {
    __shared__ int sh[256];
    int t = threadIdx.x;
    sh[t] = (t < NB) ? bcur[t] : 0;
    __syncthreads();
    for (int d = 1; d < 256; d <<= 1) {
        int v = (t >= d) ? sh[t - d] : 0;
        __syncthreads();
        sh[t] += v;
        __syncthreads();
    }
    if (t < NB) bbase[t + 1] = sh[t];
    if (t == 0) bbase[0] = 0;
}

// ---------------- Phase B: per-bucket LDS counting sort ----------------
// One block per bucket. Produces es (CSR-ordered srcs), rowptr, dinv for its
// 512 nodes. All global writes are contiguous streams.

__global__ __launch_bounds__(256) void binB_kernel(
        const int* __restrict__ bcur, const int* __restrict__ bbase,
        const int* __restrict__ pk, int* __restrict__ es,
        int* __restrict__ rowptr, float* __restrict__ dinv, int N, int NB) {
    __shared__ int cur[BK2];      // 2 KB: counts -> cursors
    __shared__ int sh[256];       // 1 KB: scan workspace
    __shared__ int esl[ESCAP];    // 48 KB: sorted srcs
    int b = blockIdx.x;
    int t = threadIdx.x;
    int node0 = b << BKSHIFT2;
    int count = bcur[b];
    int base = bbase[b];
    const int* pb = pk + (size_t)b * BKCAP;

    for (int v = t; v < BK2; v += 256) cur[v] = 0;
    __syncthreads();
    // histogram of local dst
    for (int i = t; i < count; i += 256)
        atomicAdd(&cur[pb[i] & (BK2 - 1)], 1);
    __syncthreads();
    // 512-entry exclusive scan (2 elems/thread)
    int c0 = cur[2 * t], c1 = cur[2 * t + 1];
    int s = c0 + c1;
    sh[t] = s;
    __syncthreads();
    for (int d = 1; d < 256; d <<= 1) {
        int v = (t >= d) ? sh[t - d] : 0;
        __syncthreads();
        sh[t] += v;
        __syncthreads();
    }
    int excl = sh[t] - s;
    int n0 = node0 + 2 * t;
    if (n0 < N) {
        rowptr[n0 + 1] = base + excl + c0;
        dinv[n0] = rsqrtf((float)c0 + 1.0f);
    }
    if (n0 + 1 < N) {
        rowptr[n0 + 2] = base + excl + c0 + c1;
        dinv[n0 + 1] = rsqrtf((float)c1 + 1.0f);
    }
    if (b == 0 && t == 0) rowptr[0] = 0;
    __syncthreads();
    cur[2 * t] = excl;
    cur[2 * t + 1] = excl + c0;
    __syncthreads();
    // scatter into LDS (counting sort)
    for (int i = t; i < count; i += 256) {
        int v = pb[i];
        int pos = atomicAdd(&cur[v & (BK2 - 1)], 1);
        if (pos < ESCAP) esl[pos] = v >> BKSHIFT2;
    }
    __syncthreads();
    // contiguous stream-out
    for (int i = t; i < count; i += 256) es[base + i] = esl[i];
}

// ---------------- FC1 (pre-propagation): y = x @ W1, bf16 out, no bias ----------------

__global__ __launch_bounds__(256) void fc1_kernel(
        const float* __restrict__ x, const float* __restrict__ W,
        ushort* __restrict__ yb, int N) {
    __shared__ float sW[DIN * NEU];   // 32 KB
    __shared__ float sx[32][DIN];     // 16 KB
    int tid = threadIdx.x;
    for (int k = tid; k < DIN * NEU; k += 256) sW[k] = W[k];
    int n0 = blockIdx.x * 32;
    for (int q = tid; q < 32 * 32; q += 256) {      // 32 rows x 32 float4
        int r = q >> 5, c4 = q & 31;
        int n = n0 + r;
        float4 v = (n < N) ? *((const float4*)(x + (size_t)n * DIN) + c4)
                           : make_float4(0.f, 0.f, 0.f, 0.f);
        *((float4*)&sx[r][0] + c4) = v;
    }
    __syncthreads();
    int j = tid & 63, wv = tid >> 6;
    int r0 = wv * 8;
    float acc[8];
#pragma unroll
    for (int r = 0; r < 8; r++) acc[r] = 0.f;
#pragma unroll 4
    for (int k = 0; k < DIN; k++) {
        float wk = sW[k * NEU + j];
#pragma unroll
        for (int r = 0; r < 8; r++) acc[r] = fmaf(sx[r0 + r][k], wk, acc[r]);
    }
#pragma unroll
    for (int r = 0; r < 8; r++) {
        int n = n0 + r0 + r;
        if (n < N) yb[(size_t)n * NEU + j] = f2bf(acc[r]);
    }
}

// ---------------- fused APPNP pull step, 64-dim bf16 rows ----------------

template <bool FINAL>
__global__ __launch_bounds__(256) void pull_kernel(
        const int* __restrict__ rowptr, const int* __restrict__ es,
        const float* __restrict__ dinv, const ushort* __restrict__ hin,
        const ushort* __restrict__ yb, const float* __restrict__ b1,
        ushort* __restrict__ hout, float* __restrict__ h2out, int N) {
    int wid = threadIdx.x >> 6;
    int lane = threadIdx.x & 63;
    int quarter = lane >> 4;
    int l16 = lane & 15;
    int node = blockIdx.x * 4 + wid;
    if (node >= N) return;
    int beg = rowptr[node], end = rowptr[node + 1];
    float dd = dinv[node];
    float4 acc0 = make_float4(0.f, 0.f, 0.f, 0.f);
    float4 acc1 = make_float4(0.f, 0.f, 0.f, 0.f);
    int deg = end - beg;
    for (int base = 0; base < deg; base += 64) {
        int myi = base + lane;
        int msrc = (myi < deg) ? es[beg + myi] : 0;
        float mns = (myi < deg) ? dinv[msrc] * dd : 0.f;
        int cnt = min(64, deg - base);
        int quads = (cnt + 3) >> 2;
        int j = 0;
        for (; j + 1 < quads; j += 2) {
            int i0 = 4 * j + quarter;
            int i1 = 4 * j + 4 + quarter;
            int s0 = __shfl(msrc, i0);
            float n0 = __shfl(mns, i0);
            int s1 = __shfl(msrc, i1);
            float n1 = __shfl(mns, i1);
            ushort4 w0 = *((const ushort4*)(hin + (size_t)s0 * NEU) + l16);
            ushort4 w1 = *((const ushort4*)(hin + (size_t)s1 * NEU) + l16);
            acc0.x = fmaf(n0, bf2f(w0.x), acc0.x);
            acc0.y = fmaf(n0, bf2f(w0.y), acc0.y);
            acc0.z = fmaf(n0, bf2f(w0.z), acc0.z);
            acc0.w = fmaf(n0, bf2f(w0.w), acc0.w);
            acc1.x = fmaf(n1, bf2f(w1.x), acc1.x);
            acc1.y = fmaf(n1, bf2f(w1.y), acc1.y);
            acc1.z = fmaf(n1, bf2f(w1.z), acc1.z);
            acc1.w = fmaf(n1, bf2f(w1.w), acc1.w);
        }
        if (j < quads) {
            int i0 = 4 * j + quarter;
            int s0 = __shfl(msrc, i0);
            float n0 = __shfl(mns, i0);
            ushort4 w0 = *((const ushort4*)(hin + (size_t)s0 * NEU) + l16);
            acc0.x = fmaf(n0, bf2f(w0.x), acc0.x);
            acc0.y = fmaf(n0, bf2f(w0.y), acc0.y);
            acc0.z = fmaf(n0, bf2f(w0.z), acc0.z);
            acc0.w = fmaf(n0, bf2f(w0.w), acc0.w);
        }
    }
    float4 acc;
    acc.x = acc0.x + acc1.x;
    acc.y = acc0.y + acc1.y;
    acc.z = acc0.z + acc1.z;
    acc.w = acc0.w + acc1.w;
    acc.x += __shfl_xor(acc.x, 16);
    acc.y += __shfl_xor(acc.y, 16);
    acc.z += __shfl_xor(acc.z, 16);
    acc.w += __shfl_xor(acc.w, 16);
    acc.x += __shfl_xor(acc.x, 32);
    acc.y += __shfl_xor(acc.y, 32);
    acc.z += __shfl_xor(acc.z, 32);
    acc.w += __shfl_xor(acc.w, 32);
    if (quarter == 0) {
        ushort4 hv = *((const ushort4*)(hin + (size_t)node * NEU) + l16);
        ushort4 xv = *((const ushort4*)(yb + (size_t)node * NEU) + l16);
        float d2 = dd * dd;
        float vx = 0.9f * (acc.x + d2 * bf2f(hv.x)) + 0.1f * bf2f(xv.x);
        float vy = 0.9f * (acc.y + d2 * bf2f(hv.y)) + 0.1f * bf2f(xv.y);
        float vz = 0.9f * (acc.z + d2 * bf2f(hv.z)) + 0.1f * bf2f(xv.z);
        float vw = 0.9f * (acc.w + d2 * bf2f(hv.w)) + 0.1f * bf2f(xv.w);
        if (FINAL) {
            float4 bb = *((const float4*)b1 + l16);
            float4 o;
            o.x = fmaxf(vx + bb.x, 0.f);
            o.y = fmaxf(vy + bb.y, 0.f);
            o.z = fmaxf(vz + bb.z, 0.f);
            o.w = fmaxf(vw + bb.w, 0.f);
            *((float4*)(h2out + (size_t)node * NEU) + l16) = o;
        } else {
            ushort4 o;
            o.x = f2bf(vx); o.y = f2bf(vy); o.z = f2bf(vz); o.w = f2bf(vw);
            *((ushort4*)(hout + (size_t)node * NEU) + l16) = o;
        }
    }
}

// ---------------- closeness logits ----------------

__global__ void logits_kernel(const float* __restrict__ cf, const float* __restrict__ cw,
                              const float* __restrict__ cb, float* __restrict__ logits, int N) {
    int i = blockIdx.x * blockDim.x + threadIdx.x;
    if (i >= N) return;
    const float4* c = (const float4*)(cf + (size_t)i * 8);
    float4 a = c[0], b = c[1];
    float s = a.x * cw[0] + a.y * cw[1] + a.z * cw[2] + a.w * cw[3]
            + b.x * cw[4] + b.y * cw[5] + b.z * cw[6] + b.w * cw[7] + cb[0];
    logits[i] = s;
}

// ---------------- per-graph offsets via binary search (batch sorted) ----------------

__global__ void boundary_kernel(const int* __restrict__ batch, int* __restrict__ offs,
                                int N, int G) {
    int g = blockIdx.x * blockDim.x + threadIdx.x;   // 0..G inclusive
    if (g > G) return;
    int lo = 0, hi = N;
    while (lo < hi) {
        int mid = (lo + hi) >> 1;
        if (batch[mid] < g) lo = mid + 1; else hi = mid;
    }
    offs[g] = lo;
}

// ---------------- segment softmax -> p (scaled by count) ----------------

__global__ __launch_bounds__(256) void softmax_kernel(
        const float* __restrict__ logits, const int* __restrict__ offs,
        float* __restrict__ p, int G) {
    int g = blockIdx.x;
    int s0 = offs[g], e0 = offs[g + 1];
    int tid = threadIdx.x;
    __shared__ float red[256];
    float m = -INFINITY;
    for (int i = s0 + tid; i < e0; i += 256) m = fmaxf(m, logits[i]);
    red[tid] = m; __syncthreads();
    for (int w = 128; w > 0; w >>= 1) {
        if (tid < w) red[tid] = fmaxf(red[tid], red[tid + w]);
        __syncthreads();
    }
    m = red[0]; __syncthreads();
    float z = 0.f;
    for (int i = s0 + tid; i < e0; i += 256) z += expf(logits[i] - m);
    red[tid] = z; __syncthreads();
    for (int w = 128; w > 0; w >>= 1) {
        if (tid < w) red[tid] += red[tid + w];
        __syncthreads();
    }
    z = red[0];
    float scale = (float)(e0 - s0) / z;
    for (int i = s0 + tid; i < e0; i += 256) p[i] = expf(logits[i] - m) * scale;
}

// ---------------- weighted segment max-pool ----------------

__global__ __launch_bounds__(256) void pool_kernel(
        const float* __restrict__ h2, const float* __restrict__ p,
        const int* __restrict__ offs, float* __restrict__ pooled, int G) {
    int g = blockIdx.x;
    int s0 = offs[g], e0 = offs[g + 1];
    int tid = threadIdx.x;
    int j = tid & 63, r = tid >> 6;
    float mx = -INFINITY;
    for (int i = s0 + r; i < e0; i += 4)
        mx = fmaxf(mx, p[i] * h2[(size_t)i * NEU + j]);
    __shared__ float red[256];
    red[tid] = mx;
    __syncthreads();
    if (r == 0) {
        float m0 = fmaxf(fmaxf(red[j], red[64 + j]), fmaxf(red[128 + j], red[192 + j]));
        pooled[(size_t)g * NEU + j] = m0;
    }
}

// ---------------- final MLP 64->16->1 ----------------

__global__ void final_kernel(const float* __restrict__ pooled, const float* __restrict__ w1,
                             const float* __restrict__ b1, const float* __restrict__ w2,
                             const float* __restrict__ b2, float* __restrict__ out, int G) {
    int g = blockIdx.x;
    int tid = threadIdx.x;   // 64 threads
    __shared__ float sp[64];
    __shared__ float sa[16];
    sp[tid] = pooled[(size_t)g * 64 + tid];
    __syncthreads();
    if (tid < 16) {
        float acc = b1[tid];
#pragma unroll
        for (int k = 0; k < 64; k++) acc = fmaf(sp[k], w1[k * 16 + tid], acc);
        sa[tid] = fmaxf(acc, 0.f);
    }
    __syncthreads();
    if (tid == 0) {
        float o = b2[0];
#pragma unroll
        for (int k = 0; k < 16; k++) o = fmaf(sa[k], w2[k], o);
        out[g] = o;
    }
}

// ---------------------------------------------------------------------------

extern "C" void kernel_launch(void* const* d_in, const int* in_sizes, int n_in,
                              void* d_out, int out_size, void* d_ws, size_t ws_size,
                              hipStream_t stream) {
    const float* x       = (const float*)d_in[0];
    const float* cf      = (const float*)d_in[1];
    const int*   ei      = (const int*)d_in[2];
    const int*   batch   = (const int*)d_in[3];
    const float* nn1_w   = (const float*)d_in[5];
    const float* nn1_b   = (const float*)d_in[6];
    const float* close_w = (const float*)d_in[7];
    const float* close_b = (const float*)d_in[8];
    const float* att1_w  = (const float*)d_in[9];
    const float* att1_b  = (const float*)d_in[10];
    const float* att2_w  = (const float*)d_in[11];
    const float* att2_b  = (const float*)d_in[12];
    float* out = (float*)d_out;

    int N = in_sizes[0] / DIN;
    int E = in_sizes[2] / 2;
    int G = out_size;

    const int* src = ei;
    const int* dst = ei + E;

    char* w = (char*)d_ws;
    size_t off = 0;
    auto alloc = [&](size_t bytes) -> void* {
        void* ptr = w + off;
        off += (bytes + 511) & ~(size_t)511;
        return ptr;
    };
    int NB = (N + BK2 - 1) >> BKSHIFT2;   // 196 for N=100K (<= MAXNB)

    ushort* yb     = (ushort*)alloc((size_t)N * NEU * 2);   // x @ W1, bf16
    ushort* hb0    = (ushort*)alloc((size_t)N * NEU * 2);
    ushort* hb1    = (ushort*)alloc((size_t)N * NEU * 2);
    float* h2      = (float*)alloc((size_t)N * NEU * 4);    // relu(prop+b1), f32
    float* dinv    = (float*)alloc((size_t)N * 4);
    int*   rowptr  = (int*)alloc(((size_t)N + 1) * 4);
    int*   es      = (int*)alloc((size_t)E * 4);
    int*   bcur    = (int*)alloc((size_t)NB * 4);
    int*   bbase   = (int*)alloc(((size_t)NB + 1) * 4);
    int*   pk      = (int*)alloc((size_t)NB * BKCAP * 4);
    float* logits  = (float*)alloc((size_t)N * 4);
    float* p       = (float*)alloc((size_t)N * 4);
    int*   offs    = (int*)alloc(((size_t)G + 1) * 4);
    float* pooled  = (float*)alloc((size_t)G * NEU * 4);
    (void)ws_size; (void)n_in;

    hipMemsetAsync(bcur, 0, (size_t)NB * 4, stream);

    // --- y = x @ W1 (propagation commutes with right-mul) ---
    fc1_kernel<<<(N + 31) / 32, 256, 0, stream>>>(x, nn1_w, yb, N);

    // --- CSR build: bin -> scan -> per-bucket LDS counting sort ---
    binA_kernel<<<256, 256, 0, stream>>>(src, dst, bcur, pk, E, NB);
    bscan_kernel<<<1, 256, 0, stream>>>(bcur, bbase, NB);
    binB_kernel<<<NB, 256, 0, stream>>>(bcur, bbase, pk, es, rowptr, dinv, N, NB);

    // --- APPNP: 3 fused pull steps in 64-dim bf16; last applies b1+relu ---
    pull_kernel<false><<<(N + 3) / 4, 256, 0, stream>>>(rowptr, es, dinv, yb,  yb, nn1_b, hb0, nullptr, N);
    pull_kernel<false><<<(N + 3) / 4, 256, 0, stream>>>(rowptr, es, dinv, hb0, yb, nn1_b, hb1, nullptr, N);
    pull_kernel<true ><<<(N + 3) / 4, 256, 0, stream>>>(rowptr, es, dinv, hb1, yb, nn1_b, nullptr, h2, N);

    // --- head ---
    logits_kernel<<<(N + 255) / 256, 256, 0, stream>>>(cf, close_w, close_b, logits, N);
    boundary_kernel<<<2, 256, 0, stream>>>(batch, offs, N, G);
    softmax_kernel<<<G, 256, 0, stream>>>(logits, offs, p, G);
    pool_kernel<<<G, 256, 0, stream>>>(h2, p, offs, pooled, G);
    final_kernel<<<G, 64, 0, stream>>>(pooled, att1_w, att1_b, att2_w, att2_b, out, G);
}

// Round 9
// 251.213 us; speedup vs baseline: 17.5144x; 1.0924x over previous
//
#include <hip/hip_runtime.h>
#include <cstdint>
#include <cstddef>

// ---------------------------------------------------------------------------
// APPNPNet_Structural: FC1-first (prop commutes with right-mul) -> APPNP K=3
// in 64-dim bf16 -> segment softmax pooling -> MLP(64->16->1).
// Round 9: fc1 via mfma_f32_16x16x32_bf16. Each wave keeps ALL of W1 as 16
// B-fragments in VGPRs, streams x rows straight from global (no LDS x stage),
// 16 MFMAs per 16-row tile. Rest unchanged from round 8.
// ---------------------------------------------------------------------------

#define DIN 128
#define NEU 64
#define BK2 512            // nodes per bucket
#define BKSHIFT2 9
#define BKCAP 16384        // per-bucket global staging capacity (mean 8192)
#define ESCAP 12288        // per-bucket LDS sort capacity (48KB)
#define MAXNB 256

typedef __attribute__((ext_vector_type(8))) short short8v;   // 8 bf16 (4 VGPRs)
typedef __attribute__((ext_vector_type(4))) float f32x4;     // 4 fp32 acc

// bf16 helpers: storage = ushort, math = f32.
__device__ inline float bf2f(unsigned short h) {
    return __uint_as_float(((unsigned)h) << 16);
}
__device__ inline unsigned short f2bf(float f) {   // round-to-nearest-even
    unsigned u = __float_as_uint(f);
    unsigned r = u + 0x7FFFu + ((u >> 16) & 1u);
    return (unsigned short)(r >> 16);
}

// ---------------- Phase A: coarse binning, packed 4B payload ----------------

__global__ __launch_bounds__(256) void binA_kernel(
        const int* __restrict__ src, const int* __restrict__ dst,
        int* __restrict__ bcur, int* __restrict__ pk, int E, int NB) {
    __shared__ int hist[MAXNB];
    __shared__ int cur[MAXNB];
    int nchunk = gridDim.x;
    int chunk = (E + nchunk - 1) / nchunk;
    int lo = blockIdx.x * chunk;
    int hi = min(E, lo + chunk);
    int t = threadIdx.x;
    for (int b = t; b < NB; b += 256) hist[b] = 0;
    __syncthreads();
    for (int i = lo + t; i < hi; i += 256)
        atomicAdd(&hist[dst[i] >> BKSHIFT2], 1);
    __syncthreads();
    for (int b = t; b < NB; b += 256)
        cur[b] = atomicAdd(&bcur[b], hist[b]);
    __syncthreads();
    for (int i = lo + t; i < hi; i += 256) {
        int d = dst[i];
        int b = d >> BKSHIFT2;
        int pos = atomicAdd(&cur[b], 1);
        pk[(size_t)b * BKCAP + pos] = (src[i] << BKSHIFT2) | (d & (BK2 - 1));
    }
}

// ---------------- exclusive scan of bucket counts ----------------

__global__ void bscan_kernel(const int* __restrict__ bcur, int* __restrict__ bbase, int NB) {
    __shared__ int sh[256];
    int t = threadIdx.x;
    sh[t] = (t < NB) ? bcur[t] : 0;
    __syncthreads();
    for (int d = 1; d < 256; d <<= 1) {
        int v = (t >= d) ? sh[t - d] : 0;
        __syncthreads();
        sh[t] += v;
        __syncthreads();
    }
    if (t < NB) bbase[t + 1] = sh[t];
    if (t == 0) bbase[0] = 0;
}

// ---------------- Phase B: per-bucket LDS counting sort ----------------

__global__ __launch_bounds__(256) void binB_kernel(
        const int* __restrict__ bcur, const int* __restrict__ bbase,
        const int* __restrict__ pk, int* __restrict__ es,
        int* __restrict__ rowptr, float* __restrict__ dinv, int N, int NB) {
    __shared__ int cur[BK2];      // 2 KB: counts -> cursors
    __shared__ int sh[256];       // 1 KB: scan workspace
    __shared__ int esl[ESCAP];    // 48 KB: sorted srcs
    int b = blockIdx.x;
    int t = threadIdx.x;
    int node0 = b << BKSHIFT2;
    int count = bcur[b];
    int base = bbase[b];
    const int* pb = pk + (size_t)b * BKCAP;

    for (int v = t; v < BK2; v += 256) cur[v] = 0;
    __syncthreads();
    for (int i = t; i < count; i += 256)
        atomicAdd(&cur[pb[i] & (BK2 - 1)], 1);
    __syncthreads();
    int c0 = cur[2 * t], c1 = cur[2 * t + 1];
    int s = c0 + c1;
    sh[t] = s;
    __syncthreads();
    for (int d = 1; d < 256; d <<= 1) {
        int v = (t >= d) ? sh[t - d] : 0;
        __syncthreads();
        sh[t] += v;
        __syncthreads();
    }
    int excl = sh[t] - s;
    int n0 = node0 + 2 * t;
    if (n0 < N) {
        rowptr[n0 + 1] = base + excl + c0;
        dinv[n0] = rsqrtf((float)c0 + 1.0f);
    }
    if (n0 + 1 < N) {
        rowptr[n0 + 2] = base + excl + c0 + c1;
        dinv[n0 + 1] = rsqrtf((float)c1 + 1.0f);
    }
    if (b == 0 && t == 0) rowptr[0] = 0;
    __syncthreads();
    cur[2 * t] = excl;
    cur[2 * t + 1] = excl + c0;
    __syncthreads();
    for (int i = t; i < count; i += 256) {
        int v = pb[i];
        int pos = atomicAdd(&cur[v & (BK2 - 1)], 1);
        if (pos < ESCAP) esl[pos] = v >> BKSHIFT2;
    }
    __syncthreads();
    for (int i = t; i < count; i += 256) es[base + i] = esl[i];
}

// ---------------- FC1 via MFMA: y = x @ W1 (bf16 in, bf16 out, no bias) ----
// Wave = 16 rows. W1 held entirely in 16 B-fragments (64 VGPRs/lane).
// A-frag: row = lane&15, k = (lane>>4)*8+e.  B-frag: col = lane&15, same k.
// C/D: col = lane&15, row = (lane>>4)*4+reg  [m89-verified].

__global__ __launch_bounds__(256) void fc1_kernel(
        const float* __restrict__ x, const float* __restrict__ W,
        ushort* __restrict__ yb, int N) {
    __shared__ ushort sW[DIN * NEU];   // bf16 W, 16 KB
    int tid = threadIdx.x;
    for (int k = tid; k < DIN * NEU / 2; k += 256) {
        float2 v = ((const float2*)W)[k];
        ushort2 o;
        o.x = f2bf(v.x);
        o.y = f2bf(v.y);
        ((ushort2*)sW)[k] = o;
    }
    __syncthreads();
    int lane = tid & 63;
    int wv = tid >> 6;
    int l15 = lane & 15;
    int lg = lane >> 4;
    // B fragments b[kt][ct]
    short8v bfrag[4][4];
#pragma unroll
    for (int kt = 0; kt < 4; kt++)
#pragma unroll
        for (int ct = 0; ct < 4; ct++) {
            short8v f;
#pragma unroll
            for (int e = 0; e < 8; e++)
                f[e] = (short)sW[(kt * 32 + lg * 8 + e) * NEU + ct * 16 + l15];
            bfrag[kt][ct] = f;
        }
    long long row0 = (long long)blockIdx.x * 64 + wv * 16;
    if (row0 >= N) return;
    bool rowok = (row0 + l15) < N;
    const float* xr = x + (size_t)(row0 + l15) * DIN;
    f32x4 acc[4];
#pragma unroll
    for (int ct = 0; ct < 4; ct++) acc[ct] = (f32x4){0.f, 0.f, 0.f, 0.f};
#pragma unroll
    for (int kt = 0; kt < 4; kt++) {
        short8v af = (short8v){0, 0, 0, 0, 0, 0, 0, 0};
        if (rowok) {
            float4 v0 = *((const float4*)(xr + kt * 32 + lg * 8));
            float4 v1 = *((const float4*)(xr + kt * 32 + lg * 8 + 4));
            af[0] = (short)f2bf(v0.x); af[1] = (short)f2bf(v0.y);
            af[2] = (short)f2bf(v0.z); af[3] = (short)f2bf(v0.w);
            af[4] = (short)f2bf(v1.x); af[5] = (short)f2bf(v1.y);
            af[6] = (short)f2bf(v1.z); af[7] = (short)f2bf(v1.w);
        }
#pragma unroll
        for (int ct = 0; ct < 4; ct++)
            acc[ct] = __builtin_amdgcn_mfma_f32_16x16x32_bf16(af, bfrag[kt][ct], acc[ct], 0, 0, 0);
    }
#pragma unroll
    for (int ct = 0; ct < 4; ct++)
#pragma unroll
        for (int r = 0; r < 4; r++) {
            long long rr = row0 + lg * 4 + r;
            if (rr < N) yb[(size_t)rr * NEU + ct * 16 + l15] = f2bf(acc[ct][r]);
        }
}

// ---------------- fused APPNP pull step, 64-dim bf16 rows ----------------

template <bool FINAL>
__global__ __launch_bounds__(256) void pull_kernel(
        const int* __restrict__ rowptr, const int* __restrict__ es,
        const float* __restrict__ dinv, const ushort* __restrict__ hin,
        const ushort* __restrict__ yb, const float* __restrict__ b1,
        ushort* __restrict__ hout, float* __restrict__ h2out, int N) {
    int wid = threadIdx.x >> 6;
    int lane = threadIdx.x & 63;
    int quarter = lane >> 4;
    int l16 = lane & 15;
    int node = blockIdx.x * 4 + wid;
    if (node >= N) return;
    int beg = rowptr[node], end = rowptr[node + 1];
    float dd = dinv[node];
    float4 acc0 = make_float4(0.f, 0.f, 0.f, 0.f);
    float4 acc1 = make_float4(0.f, 0.f, 0.f, 0.f);
    int deg = end - beg;
    for (int base = 0; base < deg; base += 64) {
        int myi = base + lane;
        int msrc = (myi < deg) ? es[beg + myi] : 0;
        float mns = (myi < deg) ? dinv[msrc] * dd : 0.f;
        int cnt = min(64, deg - base);
        int quads = (cnt + 3) >> 2;
        int j = 0;
        for (; j + 1 < quads; j += 2) {
            int i0 = 4 * j + quarter;
            int i1 = 4 * j + 4 + quarter;
            int s0 = __shfl(msrc, i0);
            float n0 = __shfl(mns, i0);
            int s1 = __shfl(msrc, i1);
            float n1 = __shfl(mns, i1);
            ushort4 w0 = *((const ushort4*)(hin + (size_t)s0 * NEU) + l16);
            ushort4 w1 = *((const ushort4*)(hin + (size_t)s1 * NEU) + l16);
            acc0.x = fmaf(n0, bf2f(w0.x), acc0.x);
            acc0.y = fmaf(n0, bf2f(w0.y), acc0.y);
            acc0.z = fmaf(n0, bf2f(w0.z), acc0.z);
            acc0.w = fmaf(n0, bf2f(w0.w), acc0.w);
            acc1.x = fmaf(n1, bf2f(w1.x), acc1.x);
            acc1.y = fmaf(n1, bf2f(w1.y), acc1.y);
            acc1.z = fmaf(n1, bf2f(w1.z), acc1.z);
            acc1.w = fmaf(n1, bf2f(w1.w), acc1.w);
        }
        if (j < quads) {
            int i0 = 4 * j + quarter;
            int s0 = __shfl(msrc, i0);
            float n0 = __shfl(mns, i0);
            ushort4 w0 = *((const ushort4*)(hin + (size_t)s0 * NEU) + l16);
            acc0.x = fmaf(n0, bf2f(w0.x), acc0.x);
            acc0.y = fmaf(n0, bf2f(w0.y), acc0.y);
            acc0.z = fmaf(n0, bf2f(w0.z), acc0.z);
            acc0.w = fmaf(n0, bf2f(w0.w), acc0.w);
        }
    }
    float4 acc;
    acc.x = acc0.x + acc1.x;
    acc.y = acc0.y + acc1.y;
    acc.z = acc0.z + acc1.z;
    acc.w = acc0.w + acc1.w;
    acc.x += __shfl_xor(acc.x, 16);
    acc.y += __shfl_xor(acc.y, 16);
    acc.z += __shfl_xor(acc.z, 16);
    acc.w += __shfl_xor(acc.w, 16);
    acc.x += __shfl_xor(acc.x, 32);
    acc.y += __shfl_xor(acc.y, 32);
    acc.z += __shfl_xor(acc.z, 32);
    acc.w += __shfl_xor(acc.w, 32);
    if (quarter == 0) {
        ushort4 hv = *((const ushort4*)(hin + (size_t)node * NEU) + l16);
        ushort4 xv = *((const ushort4*)(yb + (size_t)node * NEU) + l16);
        float d2 = dd * dd;
        float vx = 0.9f * (acc.x + d2 * bf2f(hv.x)) + 0.1f * bf2f(xv.x);
        float vy = 0.9f * (acc.y + d2 * bf2f(hv.y)) + 0.1f * bf2f(xv.y);
        float vz = 0.9f * (acc.z + d2 * bf2f(hv.z)) + 0.1f * bf2f(xv.z);
        float vw = 0.9f * (acc.w + d2 * bf2f(hv.w)) + 0.1f * bf2f(xv.w);
        if (FINAL) {
            float4 bb = *((const float4*)b1 + l16);
            float4 o;
            o.x = fmaxf(vx + bb.x, 0.f);
            o.y = fmaxf(vy + bb.y, 0.f);
            o.z = fmaxf(vz + bb.z, 0.f);
            o.w = fmaxf(vw + bb.w, 0.f);
            *((float4*)(h2out + (size_t)node * NEU) + l16) = o;
        } else {
            ushort4 o;
            o.x = f2bf(vx); o.y = f2bf(vy); o.z = f2bf(vz); o.w = f2bf(vw);
            *((ushort4*)(hout + (size_t)node * NEU) + l16) = o;
        }
    }
}

// ---------------- closeness logits ----------------

__global__ void logits_kernel(const float* __restrict__ cf, const float* __restrict__ cw,
                              const float* __restrict__ cb, float* __restrict__ logits, int N) {
    int i = blockIdx.x * blockDim.x + threadIdx.x;
    if (i >= N) return;
    const float4* c = (const float4*)(cf + (size_t)i * 8);
    float4 a = c[0], b = c[1];
    float s = a.x * cw[0] + a.y * cw[1] + a.z * cw[2] + a.w * cw[3]
            + b.x * cw[4] + b.y * cw[5] + b.z * cw[6] + b.w * cw[7] + cb[0];
    logits[i] = s;
}

// ---------------- per-graph offsets via binary search (batch sorted) ----------------

__global__ void boundary_kernel(const int* __restrict__ batch, int* __restrict__ offs,
                                int N, int G) {
    int g = blockIdx.x * blockDim.x + threadIdx.x;   // 0..G inclusive
    if (g > G) return;
    int lo = 0, hi = N;
    while (lo < hi) {
        int mid = (lo + hi) >> 1;
        if (batch[mid] < g) lo = mid + 1; else hi = mid;
    }
    offs[g] = lo;
}

// ---------------- segment softmax -> p (scaled by count) ----------------

__global__ __launch_bounds__(256) void softmax_kernel(
        const float* __restrict__ logits, const int* __restrict__ offs,
        float* __restrict__ p, int G) {
    int g = blockIdx.x;
    int s0 = offs[g], e0 = offs[g + 1];
    int tid = threadIdx.x;
    __shared__ float red[256];
    float m = -INFINITY;
    for (int i = s0 + tid; i < e0; i += 256) m = fmaxf(m, logits[i]);
    red[tid] = m; __syncthreads();
    for (int w = 128; w > 0; w >>= 1) {
        if (tid < w) red[tid] = fmaxf(red[tid], red[tid + w]);
        __syncthreads();
    }
    m = red[0]; __syncthreads();
    float z = 0.f;
    for (int i = s0 + tid; i < e0; i += 256) z += expf(logits[i] - m);
    red[tid] = z; __syncthreads();
    for (int w = 128; w > 0; w >>= 1) {
        if (tid < w) red[tid] += red[tid + w];
        __syncthreads();
    }
    z = red[0];
    float scale = (float)(e0 - s0) / z;
    for (int i = s0 + tid; i < e0; i += 256) p[i] = expf(logits[i] - m) * scale;
}

// ---------------- weighted segment max-pool ----------------

__global__ __launch_bounds__(256) void pool_kernel(
        const float* __restrict__ h2, const float* __restrict__ p,
        const int* __restrict__ offs, float* __restrict__ pooled, int G) {
    int g = blockIdx.x;
    int s0 = offs[g], e0 = offs[g + 1];
    int tid = threadIdx.x;
    int j = tid & 63, r = tid >> 6;
    float mx = -INFINITY;
    for (int i = s0 + r; i < e0; i += 4)
        mx = fmaxf(mx, p[i] * h2[(size_t)i * NEU + j]);
    __shared__ float red[256];
    red[tid] = mx;
    __syncthreads();
    if (r == 0) {
        float m0 = fmaxf(fmaxf(red[j], red[64 + j]), fmaxf(red[128 + j], red[192 + j]));
        pooled[(size_t)g * NEU + j] = m0;
    }
}

// ---------------- final MLP 64->16->1 ----------------

__global__ void final_kernel(const float* __restrict__ pooled, const float* __restrict__ w1,
                             const float* __restrict__ b1, const float* __restrict__ w2,
                             const float* __restrict__ b2, float* __restrict__ out, int G) {
    int g = blockIdx.x;
    int tid = threadIdx.x;   // 64 threads
    __shared__ float sp[64];
    __shared__ float sa[16];
    sp[tid] = pooled[(size_t)g * 64 + tid];
    __syncthreads();
    if (tid < 16) {
        float acc = b1[tid];
#pragma unroll
        for (int k = 0; k < 64; k++) acc = fmaf(sp[k], w1[k * 16 + tid], acc);
        sa[tid] = fmaxf(acc, 0.f);
    }
    __syncthreads();
    if (tid == 0) {
        float o = b2[0];
#pragma unroll
        for (int k = 0; k < 16; k++) o = fmaf(sa[k], w2[k], o);
        out[g] = o;
    }
}

// ---------------------------------------------------------------------------

extern "C" void kernel_launch(void* const* d_in, const int* in_sizes, int n_in,
                              void* d_out, int out_size, void* d_ws, size_t ws_size,
                              hipStream_t stream) {
    const float* x       = (const float*)d_in[0];
    const float* cf      = (const float*)d_in[1];
    const int*   ei      = (const int*)d_in[2];
    const int*   batch   = (const int*)d_in[3];
    const float* nn1_w   = (const float*)d_in[5];
    const float* nn1_b   = (const float*)d_in[6];
    const float* close_w = (const float*)d_in[7];
    const float* close_b = (const float*)d_in[8];
    const float* att1_w  = (const float*)d_in[9];
    const float* att1_b  = (const float*)d_in[10];
    const float* att2_w  = (const float*)d_in[11];
    const float* att2_b  = (const float*)d_in[12];
    float* out = (float*)d_out;

    int N = in_sizes[0] / DIN;
    int E = in_sizes[2] / 2;
    int G = out_size;

    const int* src = ei;
    const int* dst = ei + E;

    char* w = (char*)d_ws;
    size_t off = 0;
    auto alloc = [&](size_t bytes) -> void* {
        void* ptr = w + off;
        off += (bytes + 511) & ~(size_t)511;
        return ptr;
    };
    int NB = (N + BK2 - 1) >> BKSHIFT2;   // 196 for N=100K (<= MAXNB)

    ushort* yb     = (ushort*)alloc((size_t)N * NEU * 2);   // x @ W1, bf16
    ushort* hb0    = (ushort*)alloc((size_t)N * NEU * 2);
    ushort* hb1    = (ushort*)alloc((size_t)N * NEU * 2);
    float* h2      = (float*)alloc((size_t)N * NEU * 4);    // relu(prop+b1), f32
    float* dinv    = (float*)alloc((size_t)N * 4);
    int*   rowptr  = (int*)alloc(((size_t)N + 1) * 4);
    int*   es      = (int*)alloc((size_t)E * 4);
    int*   bcur    = (int*)alloc((size_t)NB * 4);
    int*   bbase   = (int*)alloc(((size_t)NB + 1) * 4);
    int*   pk      = (int*)alloc((size_t)NB * BKCAP * 4);
    float* logits  = (float*)alloc((size_t)N * 4);
    float* p       = (float*)alloc((size_t)N * 4);
    int*   offs    = (int*)alloc(((size_t)G + 1) * 4);
    float* pooled  = (float*)alloc((size_t)G * NEU * 4);
    (void)ws_size; (void)n_in;

    hipMemsetAsync(bcur, 0, (size_t)NB * 4, stream);

    // --- y = x @ W1 via MFMA (propagation commutes with right-mul) ---
    fc1_kernel<<<(N + 63) / 64, 256, 0, stream>>>(x, nn1_w, yb, N);

    // --- CSR build: bin -> scan -> per-bucket LDS counting sort ---
    binA_kernel<<<256, 256, 0, stream>>>(src, dst, bcur, pk, E, NB);
    bscan_kernel<<<1, 256, 0, stream>>>(bcur, bbase, NB);
    binB_kernel<<<NB, 256, 0, stream>>>(bcur, bbase, pk, es, rowptr, dinv, N, NB);

    // --- APPNP: 3 fused pull steps in 64-dim bf16; last applies b1+relu ---
    pull_kernel<false><<<(N + 3) / 4, 256, 0, stream>>>(rowptr, es, dinv, yb,  yb, nn1_b, hb0, nullptr, N);
    pull_kernel<false><<<(N + 3) / 4, 256, 0, stream>>>(rowptr, es, dinv, hb0, yb, nn1_b, hb1, nullptr, N);
    pull_kernel<true ><<<(N + 3) / 4, 256, 0, stream>>>(rowptr, es, dinv, hb1, yb, nn1_b, nullptr, h2, N);

    // --- head ---
    logits_kernel<<<(N + 255) / 256, 256, 0, stream>>>(cf, close_w, close_b, logits, N);
    boundary_kernel<<<2, 256, 0, stream>>>(batch, offs, N, G);
    softmax_kernel<<<G, 256, 0, stream>>>(logits, offs, p, G);
    pool_kernel<<<G, 256, 0, stream>>>(h2, p, offs, pooled, G);
    final_kernel<<<G, 64, 0, stream>>>(pooled, att1_w, att1_b, att2_w, att2_b, out, G);
}

// Round 10
// 239.503 us; speedup vs baseline: 18.3707x; 1.0489x over previous
//
#include <hip/hip_runtime.h>
#include <cstdint>
#include <cstddef>

// ---------------------------------------------------------------------------
// APPNPNet_Structural: FC1-first (prop commutes with right-mul) -> APPNP K=3
// in 64-dim bf16 -> segment softmax pooling -> MLP(64->16->1).
// Round 10: pulls propagate PRE-SCALED rows g = dinv*h (kills per-edge dinv
// gather + norm fma + half the shfls; inner loop = gather+add only), zero-row
// padded (branchless), 4-deep unrolled (4 gathers in flight).
// ---------------------------------------------------------------------------

#define DIN 128
#define NEU 64
#define BK2 512            // nodes per bucket
#define BKSHIFT2 9
#define BKCAP 16384        // per-bucket global staging capacity (mean 8192)
#define ESCAP 12288        // per-bucket LDS sort capacity (48KB)
#define MAXNB 256

typedef __attribute__((ext_vector_type(8))) short short8v;   // 8 bf16 (4 VGPRs)
typedef __attribute__((ext_vector_type(4))) float f32x4;     // 4 fp32 acc

// bf16 helpers: storage = ushort, math = f32.
__device__ inline float bf2f(unsigned short h) {
    return __uint_as_float(((unsigned)h) << 16);
}
__device__ inline unsigned short f2bf(float f) {   // round-to-nearest-even
    unsigned u = __float_as_uint(f);
    unsigned r = u + 0x7FFFu + ((u >> 16) & 1u);
    return (unsigned short)(r >> 16);
}

// ---------------- Phase A: coarse binning, packed 4B payload ----------------

__global__ __launch_bounds__(256) void binA_kernel(
        const int* __restrict__ src, const int* __restrict__ dst,
        int* __restrict__ bcur, int* __restrict__ pk, int E, int NB) {
    __shared__ int hist[MAXNB];
    __shared__ int cur[MAXNB];
    int nchunk = gridDim.x;
    int chunk = (E + nchunk - 1) / nchunk;
    int lo = blockIdx.x * chunk;
    int hi = min(E, lo + chunk);
    int t = threadIdx.x;
    for (int b = t; b < NB; b += 256) hist[b] = 0;
    __syncthreads();
    for (int i = lo + t; i < hi; i += 256)
        atomicAdd(&hist[dst[i] >> BKSHIFT2], 1);
    __syncthreads();
    for (int b = t; b < NB; b += 256)
        cur[b] = atomicAdd(&bcur[b], hist[b]);
    __syncthreads();
    for (int i = lo + t; i < hi; i += 256) {
        int d = dst[i];
        int b = d >> BKSHIFT2;
        int pos = atomicAdd(&cur[b], 1);
        pk[(size_t)b * BKCAP + pos] = (src[i] << BKSHIFT2) | (d & (BK2 - 1));
    }
}

// ---------------- exclusive scan of bucket counts ----------------

__global__ void bscan_kernel(const int* __restrict__ bcur, int* __restrict__ bbase, int NB) {
    __shared__ int sh[256];
    int t = threadIdx.x;
    sh[t] = (t < NB) ? bcur[t] : 0;
    __syncthreads();
    for (int d = 1; d < 256; d <<= 1) {
        int v = (t >= d) ? sh[t - d] : 0;
        __syncthreads();
        sh[t] += v;
        __syncthreads();
    }
    if (t < NB) bbase[t + 1] = sh[t];
    if (t == 0) bbase[0] = 0;
}

// ---------------- Phase B: per-bucket LDS counting sort ----------------

__global__ __launch_bounds__(256) void binB_kernel(
        const int* __restrict__ bcur, const int* __restrict__ bbase,
        const int* __restrict__ pk, int* __restrict__ es,
        int* __restrict__ rowptr, float* __restrict__ dinv, int N, int NB) {
    __shared__ int cur[BK2];      // 2 KB: counts -> cursors
    __shared__ int sh[256];       // 1 KB: scan workspace
    __shared__ int esl[ESCAP];    // 48 KB: sorted srcs
    int b = blockIdx.x;
    int t = threadIdx.x;
    int node0 = b << BKSHIFT2;
    int count = bcur[b];
    int base = bbase[b];
    const int* pb = pk + (size_t)b * BKCAP;

    for (int v = t; v < BK2; v += 256) cur[v] = 0;
    __syncthreads();
    for (int i = t; i < count; i += 256)
        atomicAdd(&cur[pb[i] & (BK2 - 1)], 1);
    __syncthreads();
    int c0 = cur[2 * t], c1 = cur[2 * t + 1];
    int s = c0 + c1;
    sh[t] = s;
    __syncthreads();
    for (int d = 1; d < 256; d <<= 1) {
        int v = (t >= d) ? sh[t - d] : 0;
        __syncthreads();
        sh[t] += v;
        __syncthreads();
    }
    int excl = sh[t] - s;
    int n0 = node0 + 2 * t;
    if (n0 < N) {
        rowptr[n0 + 1] = base + excl + c0;
        dinv[n0] = rsqrtf((float)c0 + 1.0f);
    }
    if (n0 + 1 < N) {
        rowptr[n0 + 2] = base + excl + c0 + c1;
        dinv[n0 + 1] = rsqrtf((float)c1 + 1.0f);
    }
    if (b == 0 && t == 0) rowptr[0] = 0;
    __syncthreads();
    cur[2 * t] = excl;
    cur[2 * t + 1] = excl + c0;
    __syncthreads();
    for (int i = t; i < count; i += 256) {
        int v = pb[i];
        int pos = atomicAdd(&cur[v & (BK2 - 1)], 1);
        if (pos < ESCAP) esl[pos] = v >> BKSHIFT2;
    }
    __syncthreads();
    for (int i = t; i < count; i += 256) es[base + i] = esl[i];
}

// ---------------- FC1 via MFMA: y = x @ W1 (bf16 in, bf16 out, no bias) ----

__global__ __launch_bounds__(256) void fc1_kernel(
        const float* __restrict__ x, const float* __restrict__ W,
        ushort* __restrict__ yb, int N) {
    __shared__ ushort sW[DIN * NEU];   // bf16 W, 16 KB
    int tid = threadIdx.x;
    for (int k = tid; k < DIN * NEU / 2; k += 256) {
        float2 v = ((const float2*)W)[k];
        ushort2 o;
        o.x = f2bf(v.x);
        o.y = f2bf(v.y);
        ((ushort2*)sW)[k] = o;
    }
    __syncthreads();
    int lane = tid & 63;
    int wv = tid >> 6;
    int l15 = lane & 15;
    int lg = lane >> 4;
    short8v bfrag[4][4];
#pragma unroll
    for (int kt = 0; kt < 4; kt++)
#pragma unroll
        for (int ct = 0; ct < 4; ct++) {
            short8v f;
#pragma unroll
            for (int e = 0; e < 8; e++)
                f[e] = (short)sW[(kt * 32 + lg * 8 + e) * NEU + ct * 16 + l15];
            bfrag[kt][ct] = f;
        }
    long long row0 = (long long)blockIdx.x * 64 + wv * 16;
    if (row0 >= N) return;
    bool rowok = (row0 + l15) < N;
    const float* xr = x + (size_t)(row0 + l15) * DIN;
    f32x4 acc[4];
#pragma unroll
    for (int ct = 0; ct < 4; ct++) acc[ct] = (f32x4){0.f, 0.f, 0.f, 0.f};
#pragma unroll
    for (int kt = 0; kt < 4; kt++) {
        short8v af = (short8v){0, 0, 0, 0, 0, 0, 0, 0};
        if (rowok) {
            float4 v0 = *((const float4*)(xr + kt * 32 + lg * 8));
            float4 v1 = *((const float4*)(xr + kt * 32 + lg * 8 + 4));
            af[0] = (short)f2bf(v0.x); af[1] = (short)f2bf(v0.y);
            af[2] = (short)f2bf(v0.z); af[3] = (short)f2bf(v0.w);
            af[4] = (short)f2bf(v1.x); af[5] = (short)f2bf(v1.y);
            af[6] = (short)f2bf(v1.z); af[7] = (short)f2bf(v1.w);
        }
#pragma unroll
        for (int ct = 0; ct < 4; ct++)
            acc[ct] = __builtin_amdgcn_mfma_f32_16x16x32_bf16(af, bfrag[kt][ct], acc[ct], 0, 0, 0);
    }
#pragma unroll
    for (int ct = 0; ct < 4; ct++)
#pragma unroll
        for (int r = 0; r < 4; r++) {
            long long rr = row0 + lg * 4 + r;
            if (rr < N) yb[(size_t)rr * NEU + ct * 16 + l15] = f2bf(acc[ct][r]);
        }
}

// ---------------- g0 = dinv * y (bf16), and zero row N of all g buffers ----

__global__ void scale_kernel(const ushort* __restrict__ yb, const float* __restrict__ dinv,
                             ushort* __restrict__ g0, ushort* __restrict__ g1,
                             ushort* __restrict__ g2, int N) {
    int i = blockIdx.x * blockDim.x + threadIdx.x;
    int stride = gridDim.x * blockDim.x;
    int total = N * 16;            // ushort4 units
    for (; i < total; i += stride) {
        int node = i >> 4;
        float dd = dinv[node];
        ushort4 v = ((const ushort4*)yb)[i];
        ushort4 o;
        o.x = f2bf(dd * bf2f(v.x));
        o.y = f2bf(dd * bf2f(v.y));
        o.z = f2bf(dd * bf2f(v.z));
        o.w = f2bf(dd * bf2f(v.w));
        ((ushort4*)g0)[i] = o;
    }
    if (blockIdx.x == 0 && threadIdx.x < 48) {   // zero pad-row N (3 buffers x 16 ushort4)
        int buf = threadIdx.x >> 4, e = threadIdx.x & 15;
        ushort* gp = (buf == 0) ? g0 : (buf == 1) ? g1 : g2;
        ((ushort4*)(gp + (size_t)N * NEU))[e] = make_ushort4(0, 0, 0, 0);
    }
}

// ---------------- fused APPNP pull step: gather+add of pre-scaled rows ------
// one 64-lane wave per dst node, 16 lanes per edge (ushort4/lane), 4 edges in
// flight. Pad lanes gather zero-row N. Epilogue: h = 0.9*dd*(acc+g[v]) +
// 0.1*y[v]; MODE0 stores g_out = dd*h (bf16); MODE1 stores relu(h+b1) (f32).

template <int MODE>
__global__ __launch_bounds__(256) void pull_kernel(
        const int* __restrict__ rowptr, const int* __restrict__ es,
        const float* __restrict__ dinv, const ushort* __restrict__ gin,
        const ushort* __restrict__ yb, const float* __restrict__ b1,
        ushort* __restrict__ gout, float* __restrict__ h2out, int N) {
    int wid = threadIdx.x >> 6;
    int lane = threadIdx.x & 63;
    int quarter = lane >> 4;
    int l16 = lane & 15;
    int node = blockIdx.x * 4 + wid;
    if (node >= N) return;
    int beg = rowptr[node], end = rowptr[node + 1];
    float dd = dinv[node];
    float4 a0 = make_float4(0.f, 0.f, 0.f, 0.f);
    float4 a1 = make_float4(0.f, 0.f, 0.f, 0.f);
    float4 a2 = make_float4(0.f, 0.f, 0.f, 0.f);
    float4 a3 = make_float4(0.f, 0.f, 0.f, 0.f);
    int deg = end - beg;
    for (int base = 0; base < deg; base += 64) {
        int myi = base + lane;
        int msrc = (myi < deg) ? es[beg + myi] : N;   // N = zero row
        int cnt = min(64, deg - base);
        int quads4 = (cnt + 15) >> 4;                 // groups of 4 quads (pad -> zero row)
        for (int j = 0; j < quads4; j++) {
            int i0 = 16 * j + quarter;
            int s0 = __shfl(msrc, i0);
            int s1 = __shfl(msrc, i0 + 4);
            int s2 = __shfl(msrc, i0 + 8);
            int s3 = __shfl(msrc, i0 + 12);
            ushort4 w0 = *((const ushort4*)(gin + (size_t)s0 * NEU) + l16);
            ushort4 w1 = *((const ushort4*)(gin + (size_t)s1 * NEU) + l16);
            ushort4 w2 = *((const ushort4*)(gin + (size_t)s2 * NEU) + l16);
            ushort4 w3 = *((const ushort4*)(gin + (size_t)s3 * NEU) + l16);
            a0.x += bf2f(w0.x); a0.y += bf2f(w0.y); a0.z += bf2f(w0.z); a0.w += bf2f(w0.w);
            a1.x += bf2f(w1.x); a1.y += bf2f(w1.y); a1.z += bf2f(w1.z); a1.w += bf2f(w1.w);
            a2.x += bf2f(w2.x); a2.y += bf2f(w2.y); a2.z += bf2f(w2.z); a2.w += bf2f(w2.w);
            a3.x += bf2f(w3.x); a3.y += bf2f(w3.y); a3.z += bf2f(w3.z); a3.w += bf2f(w3.w);
        }
    }
    float4 acc;
    acc.x = (a0.x + a1.x) + (a2.x + a3.x);
    acc.y = (a0.y + a1.y) + (a2.y + a3.y);
    acc.z = (a0.z + a1.z) + (a2.z + a3.z);
    acc.w = (a0.w + a1.w) + (a2.w + a3.w);
    acc.x += __shfl_xor(acc.x, 16);
    acc.y += __shfl_xor(acc.y, 16);
    acc.z += __shfl_xor(acc.z, 16);
    acc.w += __shfl_xor(acc.w, 16);
    acc.x += __shfl_xor(acc.x, 32);
    acc.y += __shfl_xor(acc.y, 32);
    acc.z += __shfl_xor(acc.z, 32);
    acc.w += __shfl_xor(acc.w, 32);
    if (quarter == 0) {
        ushort4 gv = *((const ushort4*)(gin + (size_t)node * NEU) + l16);
        ushort4 yv = *((const ushort4*)(yb + (size_t)node * NEU) + l16);
        float c9 = 0.9f * dd;
        float hx = c9 * (acc.x + bf2f(gv.x)) + 0.1f * bf2f(yv.x);
        float hy = c9 * (acc.y + bf2f(gv.y)) + 0.1f * bf2f(yv.y);
        float hz = c9 * (acc.z + bf2f(gv.z)) + 0.1f * bf2f(yv.z);
        float hw = c9 * (acc.w + bf2f(gv.w)) + 0.1f * bf2f(yv.w);
        if (MODE == 1) {
            float4 bb = *((const float4*)b1 + l16);
            float4 o;
            o.x = fmaxf(hx + bb.x, 0.f);
            o.y = fmaxf(hy + bb.y, 0.f);
            o.z = fmaxf(hz + bb.z, 0.f);
            o.w = fmaxf(hw + bb.w, 0.f);
            *((float4*)(h2out + (size_t)node * NEU) + l16) = o;
        } else {
            ushort4 o;
            o.x = f2bf(dd * hx); o.y = f2bf(dd * hy);
            o.z = f2bf(dd * hz); o.w = f2bf(dd * hw);
            *((ushort4*)(gout + (size_t)node * NEU) + l16) = o;
        }
    }
}

// ---------------- closeness logits ----------------

__global__ void logits_kernel(const float* __restrict__ cf, const float* __restrict__ cw,
                              const float* __restrict__ cb, float* __restrict__ logits, int N) {
    int i = blockIdx.x * blockDim.x + threadIdx.x;
    if (i >= N) return;
    const float4* c = (const float4*)(cf + (size_t)i * 8);
    float4 a = c[0], b = c[1];
    float s = a.x * cw[0] + a.y * cw[1] + a.z * cw[2] + a.w * cw[3]
            + b.x * cw[4] + b.y * cw[5] + b.z * cw[6] + b.w * cw[7] + cb[0];
    logits[i] = s;
}

// ---------------- per-graph offsets via binary search (batch sorted) ----------------

__global__ void boundary_kernel(const int* __restrict__ batch, int* __restrict__ offs,
                                int N, int G) {
    int g = blockIdx.x * blockDim.x + threadIdx.x;   // 0..G inclusive
    if (g > G) return;
    int lo = 0, hi = N;
    while (lo < hi) {
        int mid = (lo + hi) >> 1;
        if (batch[mid] < g) lo = mid + 1; else hi = mid;
    }
    offs[g] = lo;
}

// ---------------- segment softmax -> p (scaled by count) ----------------

__global__ __launch_bounds__(256) void softmax_kernel(
        const float* __restrict__ logits, const int* __restrict__ offs,
        float* __restrict__ p, int G) {
    int g = blockIdx.x;
    int s0 = offs[g], e0 = offs[g + 1];
    int tid = threadIdx.x;
    __shared__ float red[256];
    float m = -INFINITY;
    for (int i = s0 + tid; i < e0; i += 256) m = fmaxf(m, logits[i]);
    red[tid] = m; __syncthreads();
    for (int w = 128; w > 0; w >>= 1) {
        if (tid < w) red[tid] = fmaxf(red[tid], red[tid + w]);
        __syncthreads();
    }
    m = red[0]; __syncthreads();
    float z = 0.f;
    for (int i = s0 + tid; i < e0; i += 256) z += expf(logits[i] - m);
    red[tid] = z; __syncthreads();
    for (int w = 128; w > 0; w >>= 1) {
        if (tid < w) red[tid] += red[tid + w];
        __syncthreads();
    }
    z = red[0];
    float scale = (float)(e0 - s0) / z;
    for (int i = s0 + tid; i < e0; i += 256) p[i] = expf(logits[i] - m) * scale;
}

// ---------------- weighted segment max-pool ----------------

__global__ __launch_bounds__(256) void pool_kernel(
        const float* __restrict__ h2, const float* __restrict__ p,
        const int* __restrict__ offs, float* __restrict__ pooled, int G) {
    int g = blockIdx.x;
    int s0 = offs[g], e0 = offs[g + 1];
    int tid = threadIdx.x;
    int j = tid & 63, r = tid >> 6;
    float mx = -INFINITY;
    for (int i = s0 + r; i < e0; i += 4)
        mx = fmaxf(mx, p[i] * h2[(size_t)i * NEU + j]);
    __shared__ float red[256];
    red[tid] = mx;
    __syncthreads();
    if (r == 0) {
        float m0 = fmaxf(fmaxf(red[j], red[64 + j]), fmaxf(red[128 + j], red[192 + j]));
        pooled[(size_t)g * NEU + j] = m0;
    }
}

// ---------------- final MLP 64->16->1 ----------------

__global__ void final_kernel(const float* __restrict__ pooled, const float* __restrict__ w1,
                             const float* __restrict__ b1, const float* __restrict__ w2,
                             const float* __restrict__ b2, float* __restrict__ out, int G) {
    int g = blockIdx.x;
    int tid = threadIdx.x;   // 64 threads
    __shared__ float sp[64];
    __shared__ float sa[16];
    sp[tid] = pooled[(size_t)g * 64 + tid];
    __syncthreads();
    if (tid < 16) {
        float acc = b1[tid];
#pragma unroll
        for (int k = 0; k < 64; k++) acc = fmaf(sp[k], w1[k * 16 + tid], acc);
        sa[tid] = fmaxf(acc, 0.f);
    }
    __syncthreads();
    if (tid == 0) {
        float o = b2[0];
#pragma unroll
        for (int k = 0; k < 16; k++) o = fmaf(sa[k], w2[k], o);
        out[g] = o;
    }
}

// ---------------------------------------------------------------------------

extern "C" void kernel_launch(void* const* d_in, const int* in_sizes, int n_in,
                              void* d_out, int out_size, void* d_ws, size_t ws_size,
                              hipStream_t stream) {
    const float* x       = (const float*)d_in[0];
    const float* cf      = (const float*)d_in[1];
    const int*   ei      = (const int*)d_in[2];
    const int*   batch   = (const int*)d_in[3];
    const float* nn1_w   = (const float*)d_in[5];
    const float* nn1_b   = (const float*)d_in[6];
    const float* close_w = (const float*)d_in[7];
    const float* close_b = (const float*)d_in[8];
    const float* att1_w  = (const float*)d_in[9];
    const float* att1_b  = (const float*)d_in[10];
    const float* att2_w  = (const float*)d_in[11];
    const float* att2_b  = (const float*)d_in[12];
    float* out = (float*)d_out;

    int N = in_sizes[0] / DIN;
    int E = in_sizes[2] / 2;
    int G = out_size;

    const int* src = ei;
    const int* dst = ei + E;

    char* w = (char*)d_ws;
    size_t off = 0;
    auto alloc = [&](size_t bytes) -> void* {
        void* ptr = w + off;
        off += (bytes + 511) & ~(size_t)511;
        return ptr;
    };
    int NB = (N + BK2 - 1) >> BKSHIFT2;   // 196 for N=100K (<= MAXNB)

    ushort* yb     = (ushort*)alloc((size_t)N * NEU * 2);          // x @ W1
    ushort* g0     = (ushort*)alloc(((size_t)N + 1) * NEU * 2);    // dinv*h bufs (+pad row)
    ushort* g1     = (ushort*)alloc(((size_t)N + 1) * NEU * 2);
    ushort* g2     = (ushort*)alloc(((size_t)N + 1) * NEU * 2);
    float* h2      = (float*)alloc((size_t)N * NEU * 4);           // relu(prop+b1), f32
    float* dinv    = (float*)alloc((size_t)N * 4);
    int*   rowptr  = (int*)alloc(((size_t)N + 1) * 4);
    int*   es      = (int*)alloc((size_t)E * 4);
    int*   bcur    = (int*)alloc((size_t)NB * 4);
    int*   bbase   = (int*)alloc(((size_t)NB + 1) * 4);
    int*   pk      = (int*)alloc((size_t)NB * BKCAP * 4);
    float* logits  = (float*)alloc((size_t)N * 4);
    float* p       = (float*)alloc((size_t)N * 4);
    int*   offs    = (int*)alloc(((size_t)G + 1) * 4);
    float* pooled  = (float*)alloc((size_t)G * NEU * 4);
    (void)ws_size; (void)n_in;

    hipMemsetAsync(bcur, 0, (size_t)NB * 4, stream);

    // --- CSR build: bin -> scan -> per-bucket LDS counting sort (makes dinv) ---
    binA_kernel<<<256, 256, 0, stream>>>(src, dst, bcur, pk, E, NB);
    bscan_kernel<<<1, 256, 0, stream>>>(bcur, bbase, NB);
    binB_kernel<<<NB, 256, 0, stream>>>(bcur, bbase, pk, es, rowptr, dinv, N, NB);

    // --- y = x @ W1 via MFMA; g0 = dinv*y ---
    fc1_kernel<<<(N + 63) / 64, 256, 0, stream>>>(x, nn1_w, yb, N);
    scale_kernel<<<2048, 256, 0, stream>>>(yb, dinv, g0, g1, g2, N);

    // --- APPNP: 3 pulls on pre-scaled rows; last applies b1+relu ---
    pull_kernel<0><<<(N + 3) / 4, 256, 0, stream>>>(rowptr, es, dinv, g0, yb, nn1_b, g1, nullptr, N);
    pull_kernel<0><<<(N + 3) / 4, 256, 0, stream>>>(rowptr, es, dinv, g1, yb, nn1_b, g2, nullptr, N);
    pull_kernel<1><<<(N + 3) / 4, 256, 0, stream>>>(rowptr, es, dinv, g2, yb, nn1_b, nullptr, h2, N);

    // --- head ---
    logits_kernel<<<(N + 255) / 256, 256, 0, stream>>>(cf, close_w, close_b, logits, N);
    boundary_kernel<<<2, 256, 0, stream>>>(batch, offs, N, G);
    softmax_kernel<<<G, 256, 0, stream>>>(logits, offs, p, G);
    pool_kernel<<<G, 256, 0, stream>>>(h2, p, offs, pooled, G);
    final_kernel<<<G, 64, 0, stream>>>(pooled, att1_w, att1_b, att2_w, att2_b, out, G);
}